// Round 2
// baseline (298.466 us; speedup 1.0000x reference)
//
#include <hip/hip_runtime.h>
#include <stdint.h>

// Problem constants
#define BB 2
#define SS 2048
#define DD 1024
#define HH 16
#define DK 64

typedef short s16x8 __attribute__((ext_vector_type(8)));
typedef float f32x4 __attribute__((ext_vector_type(4)));
typedef unsigned short u16x4 __attribute__((ext_vector_type(4)));

static __device__ __forceinline__ unsigned short f2bf(float f) {
  unsigned int u = __builtin_bit_cast(unsigned int, f);
  u = (u + 0x7fffu + ((u >> 16) & 1u)) >> 16;
  return (unsigned short)u;
}

static __device__ __forceinline__ f32x4 mfma16(s16x8 a, s16x8 b, f32x4 c) {
  return __builtin_amdgcn_mfma_f32_16x16x32_bf16(a, b, c, 0, 0, 0);
}

static __device__ __forceinline__ void gload_lds16(const void* g, void* l) {
  __builtin_amdgcn_global_load_lds(
      (const __attribute__((address_space(1))) unsigned int*)g,
      (__attribute__((address_space(3))) unsigned int*)l, 16, 0, 0);
}

// ---------------- fp32 -> bf16 elementwise convert (vectorized) ----------------
__global__ __launch_bounds__(256) void cvt_kernel(const float* __restrict__ in,
                                                  unsigned short* __restrict__ out,
                                                  int n4) {
  int i = blockIdx.x * 256 + threadIdx.x;
  if (i < n4) {
    f32x4 v = ((const f32x4*)in)[i];
    u16x4 o;
    o.x = f2bf(v.x); o.y = f2bf(v.y); o.z = f2bf(v.z); o.w = f2bf(v.w);
    ((u16x4*)out)[i] = o;
  }
}

// ---------------- W [K][N] fp32 -> WT [N][K] bf16 (with scale) ----------------
__global__ __launch_bounds__(256) void transpose_w_kernel(const float* __restrict__ W,
                                                          unsigned short* __restrict__ WT,
                                                          float scale) {
  __shared__ float t[32][33];
  int n0 = blockIdx.x * 32, k0 = blockIdx.y * 32;
  int tx = threadIdx.x, ty = threadIdx.y;
  for (int i = 0; i < 4; ++i)
    t[ty + 8 * i][tx] = W[(size_t)(k0 + ty + 8 * i) * DD + n0 + tx];
  __syncthreads();
  for (int i = 0; i < 4; ++i)
    WT[(size_t)(n0 + ty + 8 * i) * DD + k0 + tx] = f2bf(t[tx][ty + 8 * i] * scale);
}

// ---------------- V [bh][S][DK] bf16 -> VT [bh][DK][S] bf16 ----------------
__global__ __launch_bounds__(256) void transpose_v_kernel(const unsigned short* __restrict__ V,
                                                          unsigned short* __restrict__ VT) {
  __shared__ unsigned short t[32][33];
  int s0 = blockIdx.x * 32, d0 = blockIdx.y * 32, bh = blockIdx.z;
  int tx = threadIdx.x, ty = threadIdx.y;
  const unsigned short* Vb = V + (size_t)bh * SS * DK;
  unsigned short* Tb = VT + (size_t)bh * DK * SS;
  for (int i = 0; i < 4; ++i)
    t[ty + 8 * i][tx] = Vb[(size_t)(s0 + ty + 8 * i) * DK + d0 + tx];
  __syncthreads();
  for (int i = 0; i < 4; ++i)
    Tb[(size_t)(d0 + ty + 8 * i) * SS + s0 + tx] = t[tx][ty + 8 * i];
}

// ---------------- GEMM: C[M=4096][N=1024] = A[M][K] @ BT[N][K]^T + bias ----------------
// mode 0: write bf16 to head layout [B][H][S][DK]   (row -> (b,s), col -> (h,dk))
// mode 1: write fp32 row-major [M][N]
__global__ __launch_bounds__(256) void gemm_kernel(const unsigned short* __restrict__ A,
                                                   const unsigned short* __restrict__ BT,
                                                   const float* __restrict__ bias,
                                                   float bscale,
                                                   void* __restrict__ outp, int mode) {
  const int K = DD;
  __shared__ __align__(16) unsigned short Alds[128 * 32];
  __shared__ __align__(16) unsigned short Blds[128 * 32];
  int tid = threadIdx.x;
  int lane = tid & 63, wave = tid >> 6;
  int g = lane >> 4, r16 = lane & 15;
  int m0 = blockIdx.y * 128, n0 = blockIdx.x * 128;
  int wm = (wave >> 1) * 64, wn = (wave & 1) * 64;

  f32x4 acc[4][4] = {};

  // staging geometry: 512 chunks of 16B per matrix; chunk c -> row=c>>2, ch=c&3
  int c0 = tid, c1 = tid + 256;
  int arow0 = c0 >> 2, arow1 = c1 >> 2;
  int as0 = (c0 & 3) ^ ((arow0 >> 1) & 3);  // pre-swizzled global chunk
  int as1 = (c1 & 3) ^ ((arow1 >> 1) & 3);

  for (int k0 = 0; k0 < K; k0 += 32) {
    __syncthreads();
    gload_lds16((const char*)(A + (size_t)(m0 + arow0) * K + k0) + as0 * 16,
                (char*)Alds + wave * 1024);
    gload_lds16((const char*)(A + (size_t)(m0 + arow1) * K + k0) + as1 * 16,
                (char*)Alds + wave * 1024 + 4096);
    gload_lds16((const char*)(BT + (size_t)(n0 + arow0) * K + k0) + as0 * 16,
                (char*)Blds + wave * 1024);
    gload_lds16((const char*)(BT + (size_t)(n0 + arow1) * K + k0) + as1 * 16,
                (char*)Blds + wave * 1024 + 4096);
    __syncthreads();

    s16x8 af[4], bfr[4];
    for (int mt = 0; mt < 4; ++mt) {
      int row = wm + mt * 16 + r16;
      int ch = g ^ ((row >> 1) & 3);
      af[mt] = *(const s16x8*)((const char*)Alds + row * 64 + ch * 16);
    }
    for (int nt = 0; nt < 4; ++nt) {
      int row = wn + nt * 16 + r16;
      int ch = g ^ ((row >> 1) & 3);
      bfr[nt] = *(const s16x8*)((const char*)Blds + row * 64 + ch * 16);
    }
    for (int mt = 0; mt < 4; ++mt)
      for (int nt = 0; nt < 4; ++nt)
        acc[mt][nt] = mfma16(af[mt], bfr[nt], acc[mt][nt]);
  }

  for (int nt = 0; nt < 4; ++nt) {
    int col = n0 + wn + nt * 16 + r16;
    float bv = bias[col] * bscale;
    for (int mt = 0; mt < 4; ++mt) {
      for (int rr = 0; rr < 4; ++rr) {
        int rowg = m0 + wm + mt * 16 + g * 4 + rr;
        float val = acc[mt][nt][rr] + bv;
        if (mode == 0) {
          int bb = rowg >> 11, s = rowg & (SS - 1);
          int h = col >> 6, dk = col & (DK - 1);
          ((unsigned short*)outp)[(((size_t)bb * HH + h) * SS + s) * DK + dk] = f2bf(val);
        } else {
          ((float*)outp)[(size_t)rowg * DD + col] = val;
        }
      }
    }
  }
}

// ---------------- causal flash attention ----------------
// Qh,Kh: [B*H][S][DK] bf16 (Q pre-scaled by 1/8 via Wq), VhT: [B*H][DK][S] bf16
// ctx out: [B][S][H][DK] bf16
__global__ __launch_bounds__(256) void attn_kernel(const unsigned short* __restrict__ Qh,
                                                   const unsigned short* __restrict__ Kh,
                                                   const unsigned short* __restrict__ VhT,
                                                   unsigned short* __restrict__ ctx) {
  __shared__ __align__(16) unsigned short Klds[32 * 64];   // [key 32][d 64], chunk ^= row&7
  __shared__ __align__(16) unsigned short Vlds[64 * 32];   // [d 64][key 32], chunk ^= (row>>1)&3
  __shared__ __align__(16) unsigned short Plds[4][16 * 40];  // per-wave P, 80B row stride

  int tid = threadIdx.x;
  int lane = tid & 63, wave = tid >> 6;
  int g = lane >> 4, r16 = lane & 15;
  int q0 = blockIdx.x * 64;
  int bh = blockIdx.y;
  int qw0 = q0 + wave * 16;

  const unsigned short* Qb = Qh + (size_t)bh * SS * DK;
  const unsigned short* Kb = Kh + (size_t)bh * SS * DK;
  const unsigned short* Vb = VhT + (size_t)bh * DK * SS;

  // Q fragments (A-operand): rows qw0+r16, k = kc*32 + g*8 .. +7
  s16x8 aq[2];
  for (int kc = 0; kc < 2; ++kc)
    aq[kc] = *(const s16x8*)(Qb + (size_t)(qw0 + r16) * DK + kc * 32 + g * 8);

  f32x4 accd[4] = {};  // [d-tile], rows g*4+rr
  float mrow[4], lrow[4];
  for (int rr = 0; rr < 4; ++rr) { mrow[rr] = -INFINITY; lrow[rr] = 0.0f; }

  // staging geometry (per thread, one 16B chunk of K and one of V^T)
  int krow = tid >> 3, kch = tid & 7;
  int kchs = kch ^ (krow & 7);
  int vrow = tid >> 2, vch = tid & 3;
  int vchs = vch ^ ((vrow >> 1) & 3);

  int kv_end = q0 + 64;
  for (int kv0 = 0; kv0 < kv_end; kv0 += 32) {
    __syncthreads();
    gload_lds16((const char*)(Kb + (size_t)(kv0 + krow) * DK) + kchs * 16,
                (char*)Klds + wave * 1024);
    gload_lds16((const char*)(Vb + (size_t)vrow * SS + kv0) + vchs * 16,
                (char*)Vlds + wave * 1024);
    __syncthreads();

    if (kv0 <= qw0 + 15) {
      // QK^T: scores D[qrow][key], 2 key-half fragments
      f32x4 sf0 = {}, sf1 = {};
      for (int kc = 0; kc < 2; ++kc) {
        int row0 = r16;
        int ch0 = (kc * 4 + g) ^ (row0 & 7);
        s16x8 bk0 = *(const s16x8*)((const char*)Klds + row0 * 128 + ch0 * 16);
        sf0 = mfma16(aq[kc], bk0, sf0);
        int row1 = 16 + r16;
        int ch1 = (kc * 4 + g) ^ (row1 & 7);
        s16x8 bk1 = *(const s16x8*)((const char*)Klds + row1 * 128 + ch1 * 16);
        sf1 = mfma16(aq[kc], bk1, sf1);
      }

      float p0[4], p1[4], fac[4];
      for (int rr = 0; rr < 4; ++rr) {
        int rowq = qw0 + g * 4 + rr;
        float s0 = sf0[rr], s1 = sf1[rr];
        if (kv0 + r16 > rowq) s0 = -INFINITY;
        if (kv0 + 16 + r16 > rowq) s1 = -INFINITY;
        float t = fmaxf(s0, s1);
        t = fmaxf(t, __shfl_xor(t, 1));
        t = fmaxf(t, __shfl_xor(t, 2));
        t = fmaxf(t, __shfl_xor(t, 4));
        t = fmaxf(t, __shfl_xor(t, 8));
        float mn = fmaxf(mrow[rr], t);
        p0[rr] = __expf(s0 - mn);
        p1[rr] = __expf(s1 - mn);
        float su = p0[rr] + p1[rr];
        su += __shfl_xor(su, 1);
        su += __shfl_xor(su, 2);
        su += __shfl_xor(su, 4);
        su += __shfl_xor(su, 8);
        fac[rr] = __expf(mrow[rr] - mn);
        lrow[rr] = lrow[rr] * fac[rr] + su;
        mrow[rr] = mn;
      }
      for (int dt = 0; dt < 4; ++dt)
        for (int rr = 0; rr < 4; ++rr) accd[dt][rr] *= fac[rr];

      // P (D-layout) -> LDS -> A-layout fragment
      unsigned short* pw = &Plds[wave][0];
      for (int rr = 0; rr < 4; ++rr) {
        int prow = g * 4 + rr;
        pw[prow * 40 + r16] = f2bf(p0[rr]);
        pw[prow * 40 + 16 + r16] = f2bf(p1[rr]);
      }
      s16x8 pa = *(const s16x8*)((const char*)pw + r16 * 80 + g * 16);

      for (int dt = 0; dt < 4; ++dt) {
        int row = dt * 16 + r16;
        int ch = g ^ ((row >> 1) & 3);
        s16x8 bv = *(const s16x8*)((const char*)Vlds + row * 64 + ch * 16);
        accd[dt] = mfma16(pa, bv, accd[dt]);
      }
    }
  }

  int b = bh >> 4, h = bh & (HH - 1);
  for (int dt = 0; dt < 4; ++dt) {
    for (int rr = 0; rr < 4; ++rr) {
      int rowq = qw0 + g * 4 + rr;
      float val = accd[dt][rr] / lrow[rr];
      ctx[(((size_t)b * SS + rowq) * HH + h) * DK + dt * 16 + r16] = f2bf(val);
    }
  }
}

extern "C" void kernel_launch(void* const* d_in, const int* in_sizes, int n_in,
                              void* d_out, int out_size, void* d_ws, size_t ws_size,
                              hipStream_t stream) {
  const float* q = (const float*)d_in[0];
  const float* k = (const float*)d_in[1];
  const float* v = (const float*)d_in[2];
  // d_in[3] = mask: exact causal tril, implemented in-kernel
  const float* Wq = (const float*)d_in[4];
  const float* bq = (const float*)d_in[5];
  const float* Wk = (const float*)d_in[6];
  const float* bk = (const float*)d_in[7];
  const float* Wv = (const float*)d_in[8];
  const float* bv = (const float*)d_in[9];
  const float* Wo = (const float*)d_in[10];
  const float* bo = (const float*)d_in[11];

  // Workspace layout (56 MB total, with dead-buffer reuse):
  //   [ 0, 8)  qb      -> later reused as ctx (qb dead after Q-projection GEMM)
  //   [ 8,16)  kb
  //   [16,24)  vb      -> later reused as VhT (vb dead after V-projection GEMM)
  //   [24,32)  WqT/WkT/WvT/WoT (2 MB each)
  //   [32,40)  Qh
  //   [40,48)  Kh
  //   [48,56)  Vh
  char* ws = (char*)d_ws;
  const size_t MB = 1ull << 20;
  unsigned short* qb = (unsigned short*)(ws + 0 * MB);
  unsigned short* kb = (unsigned short*)(ws + 8 * MB);
  unsigned short* vb = (unsigned short*)(ws + 16 * MB);
  unsigned short* WqT = (unsigned short*)(ws + 24 * MB);
  unsigned short* WkT = (unsigned short*)(ws + 26 * MB);
  unsigned short* WvT = (unsigned short*)(ws + 28 * MB);
  unsigned short* WoT = (unsigned short*)(ws + 30 * MB);
  unsigned short* Qh = (unsigned short*)(ws + 32 * MB);
  unsigned short* Kh = (unsigned short*)(ws + 40 * MB);
  unsigned short* Vh = (unsigned short*)(ws + 48 * MB);
  unsigned short* VhT = (unsigned short*)(ws + 16 * MB);  // reuse vb
  unsigned short* ctx = (unsigned short*)(ws + 0 * MB);   // reuse qb

  const int n4 = BB * SS * DD / 4;  // 1M float4 groups

  cvt_kernel<<<n4 / 256, 256, 0, stream>>>(q, qb, n4);
  cvt_kernel<<<n4 / 256, 256, 0, stream>>>(k, kb, n4);
  cvt_kernel<<<n4 / 256, 256, 0, stream>>>(v, vb, n4);

  dim3 tb(32, 8);
  transpose_w_kernel<<<dim3(32, 32), tb, 0, stream>>>(Wq, WqT, 0.125f);  // fold 1/sqrt(DK)
  transpose_w_kernel<<<dim3(32, 32), tb, 0, stream>>>(Wk, WkT, 1.0f);
  transpose_w_kernel<<<dim3(32, 32), tb, 0, stream>>>(Wv, WvT, 1.0f);
  transpose_w_kernel<<<dim3(32, 32), tb, 0, stream>>>(Wo, WoT, 1.0f);

  gemm_kernel<<<dim3(8, 32), 256, 0, stream>>>(qb, WqT, bq, 0.125f, Qh, 0);
  gemm_kernel<<<dim3(8, 32), 256, 0, stream>>>(kb, WkT, bk, 1.0f, Kh, 0);
  gemm_kernel<<<dim3(8, 32), 256, 0, stream>>>(vb, WvT, bv, 1.0f, Vh, 0);

  transpose_v_kernel<<<dim3(SS / 32, DK / 32, BB * HH), tb, 0, stream>>>(Vh, VhT);

  attn_kernel<<<dim3(SS / 64, BB * HH), 256, 0, stream>>>(Qh, Kh, VhT, ctx);

  gemm_kernel<<<dim3(8, 32), 256, 0, stream>>>(ctx, WoT, bo, 1.0f, d_out, 1);
}

// Round 3
// 263.561 us; speedup vs baseline: 1.1324x; 1.1324x over previous
//
#include <hip/hip_runtime.h>
#include <stdint.h>

// Problem constants
#define BB 2
#define SS 2048
#define DD 1024
#define HH 16
#define DK 64

typedef short s16x8 __attribute__((ext_vector_type(8)));
typedef float f32x4 __attribute__((ext_vector_type(4)));
typedef unsigned short u16x4 __attribute__((ext_vector_type(4)));

static __device__ __forceinline__ unsigned short f2bf(float f) {
  unsigned int u = __builtin_bit_cast(unsigned int, f);
  u = (u + 0x7fffu + ((u >> 16) & 1u)) >> 16;
  return (unsigned short)u;
}

static __device__ __forceinline__ f32x4 mfma16(s16x8 a, s16x8 b, f32x4 c) {
  return __builtin_amdgcn_mfma_f32_16x16x32_bf16(a, b, c, 0, 0, 0);
}

static __device__ __forceinline__ void gload_lds16(const void* g, void* l) {
  __builtin_amdgcn_global_load_lds(
      (const __attribute__((address_space(1))) unsigned int*)g,
      (__attribute__((address_space(3))) unsigned int*)l, 16, 0, 0);
}

// ---------------- fp32 -> bf16 elementwise convert (vectorized) ----------------
__global__ __launch_bounds__(256) void cvt_kernel(const float* __restrict__ in,
                                                  unsigned short* __restrict__ out,
                                                  int n4) {
  int i = blockIdx.x * 256 + threadIdx.x;
  if (i < n4) {
    f32x4 v = ((const f32x4*)in)[i];
    u16x4 o;
    o.x = f2bf(v.x); o.y = f2bf(v.y); o.z = f2bf(v.z); o.w = f2bf(v.w);
    ((u16x4*)out)[i] = o;
  }
}

// ---------------- W [K][N] fp32 -> WT [N][K] bf16 (with scale) ----------------
__global__ __launch_bounds__(256) void transpose_w_kernel(const float* __restrict__ W,
                                                          unsigned short* __restrict__ WT,
                                                          float scale) {
  __shared__ float t[32][33];
  int n0 = blockIdx.x * 32, k0 = blockIdx.y * 32;
  int tx = threadIdx.x, ty = threadIdx.y;
  for (int i = 0; i < 4; ++i)
    t[ty + 8 * i][tx] = W[(size_t)(k0 + ty + 8 * i) * DD + n0 + tx];
  __syncthreads();
  for (int i = 0; i < 4; ++i)
    WT[(size_t)(n0 + ty + 8 * i) * DD + k0 + tx] = f2bf(t[tx][ty + 8 * i] * scale);
}

// ---------------- V [bh][S][DK] bf16 -> VT [bh][DK][S] bf16 ----------------
__global__ __launch_bounds__(256) void transpose_v_kernel(const unsigned short* __restrict__ V,
                                                          unsigned short* __restrict__ VT) {
  __shared__ unsigned short t[32][33];
  int s0 = blockIdx.x * 32, d0 = blockIdx.y * 32, bh = blockIdx.z;
  int tx = threadIdx.x, ty = threadIdx.y;
  const unsigned short* Vb = V + (size_t)bh * SS * DK;
  unsigned short* Tb = VT + (size_t)bh * DK * SS;
  for (int i = 0; i < 4; ++i)
    t[ty + 8 * i][tx] = Vb[(size_t)(s0 + ty + 8 * i) * DK + d0 + tx];
  __syncthreads();
  for (int i = 0; i < 4; ++i)
    Tb[(size_t)(d0 + ty + 8 * i) * SS + s0 + tx] = t[tx][ty + 8 * i];
}

// ---------------- projection GEMM: [4096][1024] @ WT[1024][1024]^T -> head layout ----------------
__global__ __launch_bounds__(256) void gemm_proj_kernel(const unsigned short* __restrict__ A,
                                                        const unsigned short* __restrict__ BT,
                                                        const float* __restrict__ bias,
                                                        float bscale,
                                                        unsigned short* __restrict__ outh) {
  const int K = DD;
  __shared__ __align__(16) unsigned short Alds[128 * 32];
  __shared__ __align__(16) unsigned short Blds[128 * 32];
  int tid = threadIdx.x;
  int lane = tid & 63, wave = tid >> 6;
  int g = lane >> 4, r16 = lane & 15;
  int m0 = blockIdx.y * 128, n0 = blockIdx.x * 128;
  int wm = (wave >> 1) * 64, wn = (wave & 1) * 64;

  f32x4 acc[4][4] = {};

  int c0 = tid, c1 = tid + 256;
  int arow0 = c0 >> 2, arow1 = c1 >> 2;
  int as0 = (c0 & 3) ^ ((arow0 >> 1) & 3);
  int as1 = (c1 & 3) ^ ((arow1 >> 1) & 3);

  for (int k0 = 0; k0 < K; k0 += 32) {
    __syncthreads();
    gload_lds16((const char*)(A + (size_t)(m0 + arow0) * K + k0) + as0 * 16,
                (char*)Alds + wave * 1024);
    gload_lds16((const char*)(A + (size_t)(m0 + arow1) * K + k0) + as1 * 16,
                (char*)Alds + wave * 1024 + 4096);
    gload_lds16((const char*)(BT + (size_t)(n0 + arow0) * K + k0) + as0 * 16,
                (char*)Blds + wave * 1024);
    gload_lds16((const char*)(BT + (size_t)(n0 + arow1) * K + k0) + as1 * 16,
                (char*)Blds + wave * 1024 + 4096);
    __syncthreads();

    s16x8 af[4], bfr[4];
    for (int mt = 0; mt < 4; ++mt) {
      int row = wm + mt * 16 + r16;
      int ch = g ^ ((row >> 1) & 3);
      af[mt] = *(const s16x8*)((const char*)Alds + row * 64 + ch * 16);
    }
    for (int nt = 0; nt < 4; ++nt) {
      int row = wn + nt * 16 + r16;
      int ch = g ^ ((row >> 1) & 3);
      bfr[nt] = *(const s16x8*)((const char*)Blds + row * 64 + ch * 16);
    }
    for (int mt = 0; mt < 4; ++mt)
      for (int nt = 0; nt < 4; ++nt)
        acc[mt][nt] = mfma16(af[mt], bfr[nt], acc[mt][nt]);
  }

  for (int nt = 0; nt < 4; ++nt) {
    int col = n0 + wn + nt * 16 + r16;
    int h = col >> 6, dk = col & (DK - 1);
    float bvv = bias[col] * bscale;
    for (int mt = 0; mt < 4; ++mt) {
      for (int rr = 0; rr < 4; ++rr) {
        int rowg = m0 + wm + mt * 16 + g * 4 + rr;
        int bb = rowg >> 11, s = rowg & (SS - 1);
        float val = acc[mt][nt][rr] + bvv;
        outh[(((size_t)bb * HH + h) * SS + s) * DK + dk] = f2bf(val);
      }
    }
  }
}

// ---------------- output GEMM: C[4096][1024] = ctx @ WoT^T + bo (fp32), 128x64 tile ----------------
__global__ __launch_bounds__(256) void gemm_out_kernel(const unsigned short* __restrict__ A,
                                                       const unsigned short* __restrict__ BT,
                                                       const float* __restrict__ bias,
                                                       float* __restrict__ out) {
  const int K = DD;
  __shared__ __align__(16) unsigned short Alds[128 * 32];
  __shared__ __align__(16) unsigned short Blds[64 * 32];
  int tid = threadIdx.x;
  int lane = tid & 63, wave = tid >> 6;
  int g = lane >> 4, r16 = lane & 15;
  int m0 = blockIdx.y * 128, n0 = blockIdx.x * 64;
  int wm = (wave >> 1) * 64, wn = (wave & 1) * 32;

  f32x4 acc[4][2] = {};

  int c0 = tid, c1 = tid + 256;
  int arow0 = c0 >> 2, arow1 = c1 >> 2;
  int as0 = (c0 & 3) ^ ((arow0 >> 1) & 3);
  int as1 = (c1 & 3) ^ ((arow1 >> 1) & 3);

  for (int k0 = 0; k0 < K; k0 += 32) {
    __syncthreads();
    gload_lds16((const char*)(A + (size_t)(m0 + arow0) * K + k0) + as0 * 16,
                (char*)Alds + wave * 1024);
    gload_lds16((const char*)(A + (size_t)(m0 + arow1) * K + k0) + as1 * 16,
                (char*)Alds + wave * 1024 + 4096);
    gload_lds16((const char*)(BT + (size_t)(n0 + arow0) * K + k0) + as0 * 16,
                (char*)Blds + wave * 1024);
    __syncthreads();

    s16x8 af[4], bfr[2];
    for (int mt = 0; mt < 4; ++mt) {
      int row = wm + mt * 16 + r16;
      int ch = g ^ ((row >> 1) & 3);
      af[mt] = *(const s16x8*)((const char*)Alds + row * 64 + ch * 16);
    }
    for (int nt = 0; nt < 2; ++nt) {
      int row = wn + nt * 16 + r16;
      int ch = g ^ ((row >> 1) & 3);
      bfr[nt] = *(const s16x8*)((const char*)Blds + row * 64 + ch * 16);
    }
    for (int mt = 0; mt < 4; ++mt)
      for (int nt = 0; nt < 2; ++nt)
        acc[mt][nt] = mfma16(af[mt], bfr[nt], acc[mt][nt]);
  }

  for (int nt = 0; nt < 2; ++nt) {
    int col = n0 + wn + nt * 16 + r16;
    float bvv = bias[col];
    for (int mt = 0; mt < 4; ++mt) {
      for (int rr = 0; rr < 4; ++rr) {
        int rowg = m0 + wm + mt * 16 + g * 4 + rr;
        out[(size_t)rowg * DD + col] = acc[mt][nt][rr] + bvv;
      }
    }
  }
}

// ---------------- causal flash attention (QBLK=128, KVBLK=64, double-buffered) ----------------
__global__ __launch_bounds__(256) void attn_kernel(const unsigned short* __restrict__ Qh,
                                                   const unsigned short* __restrict__ Kh,
                                                   const unsigned short* __restrict__ VhT,
                                                   unsigned short* __restrict__ ctx) {
  __shared__ __align__(16) unsigned short Klds[2][64 * 64];   // [key][d], 128B rows, ch ^= row&7
  __shared__ __align__(16) unsigned short Vlds[2][64 * 64];   // [d][key], 128B rows, ch ^= row&7
  __shared__ __align__(16) unsigned short Plds[4][32 * 72];   // per-wave P[32 q][64 k], 144B rows

  int tid = threadIdx.x;
  int lane = tid & 63, wave = tid >> 6;
  int g = lane >> 4, r16 = lane & 15;
  int q0 = (int)(gridDim.x - 1 - blockIdx.x) * 128;  // big blocks dispatch first
  int bh = blockIdx.y;
  int qw0 = q0 + wave * 32;

  const unsigned short* Qb = Qh + (size_t)bh * SS * DK;
  const char* Kb = (const char*)(Kh + (size_t)bh * SS * DK);
  const char* Vb = (const char*)(VhT + (size_t)bh * DK * SS);

  s16x8 aq[2][2];
  for (int mt = 0; mt < 2; ++mt)
    for (int kc = 0; kc < 2; ++kc)
      aq[mt][kc] = *(const s16x8*)(Qb + (size_t)(qw0 + mt * 16 + r16) * DK + kc * 32 + g * 8);

  f32x4 accd[2][4] = {};
  float mrow[2][4], lrow[2][4];
  for (int mt = 0; mt < 2; ++mt)
    for (int rr = 0; rr < 4; ++rr) { mrow[mt][rr] = -INFINITY; lrow[mt][rr] = 0.0f; }

  int c0 = tid, c1 = tid + 256;
  int row0 = c0 >> 3, row1 = c1 >> 3;
  int sc0 = (c0 & 7) ^ (row0 & 7);
  int sc1 = (c1 & 7) ^ (row1 & 7);

#define STAGE_KV(buf, kv0)                                                   \
  do {                                                                       \
    gload_lds16(Kb + ((size_t)((kv0) + row0) * 128) + sc0 * 16,              \
                (char*)Klds[buf] + wave * 1024);                             \
    gload_lds16(Kb + ((size_t)((kv0) + row1) * 128) + sc1 * 16,              \
                (char*)Klds[buf] + wave * 1024 + 4096);                      \
    gload_lds16(Vb + ((size_t)row0 * SS + (kv0)) * 2 + sc0 * 16,             \
                (char*)Vlds[buf] + wave * 1024);                             \
    gload_lds16(Vb + ((size_t)row1 * SS + (kv0)) * 2 + sc1 * 16,             \
                (char*)Vlds[buf] + wave * 1024 + 4096);                      \
  } while (0)

  int ntiles = q0 / 64 + 2;
  STAGE_KV(0, 0);
  int cur = 0;

  for (int t = 0; t < ntiles; ++t) {
    int kv0 = t * 64;
    __syncthreads();  // implicit vmcnt(0) drain: buf[cur] ready, buf[cur^1] reads done
    if (t + 1 < ntiles) STAGE_KV(cur ^ 1, kv0 + 64);

    if (kv0 <= qw0 + 31) {
      const char* Kc = (const char*)Klds[cur];
      const char* Vc = (const char*)Vlds[cur];

      f32x4 sf[2][4] = {};
      for (int kc = 0; kc < 2; ++kc) {
        s16x8 bk[4];
        for (int nt = 0; nt < 4; ++nt) {
          int row = nt * 16 + r16;
          int ch = (kc * 4 + g) ^ (row & 7);
          bk[nt] = *(const s16x8*)(Kc + row * 128 + ch * 16);
        }
        for (int mt = 0; mt < 2; ++mt)
          for (int nt = 0; nt < 4; ++nt)
            sf[mt][nt] = mfma16(aq[mt][kc], bk[nt], sf[mt][nt]);
      }

      bool domask = (kv0 + 63 > qw0);
      float fac[2][4];
      unsigned short* pw0 = &Plds[wave][0];
      for (int mt = 0; mt < 2; ++mt) {
        for (int rr = 0; rr < 4; ++rr) {
          int rowq = qw0 + mt * 16 + g * 4 + rr;
          float s0 = sf[mt][0][rr], s1 = sf[mt][1][rr];
          float s2 = sf[mt][2][rr], s3 = sf[mt][3][rr];
          if (domask) {
            if (kv0 + r16 > rowq) s0 = -INFINITY;
            if (kv0 + 16 + r16 > rowq) s1 = -INFINITY;
            if (kv0 + 32 + r16 > rowq) s2 = -INFINITY;
            if (kv0 + 48 + r16 > rowq) s3 = -INFINITY;
          }
          float tm = fmaxf(fmaxf(s0, s1), fmaxf(s2, s3));
          tm = fmaxf(tm, __shfl_xor(tm, 1));
          tm = fmaxf(tm, __shfl_xor(tm, 2));
          tm = fmaxf(tm, __shfl_xor(tm, 4));
          tm = fmaxf(tm, __shfl_xor(tm, 8));
          float mn = fmaxf(mrow[mt][rr], tm);
          float p0 = __expf(s0 - mn), p1 = __expf(s1 - mn);
          float p2 = __expf(s2 - mn), p3 = __expf(s3 - mn);
          float su = (p0 + p1) + (p2 + p3);
          su += __shfl_xor(su, 1);
          su += __shfl_xor(su, 2);
          su += __shfl_xor(su, 4);
          su += __shfl_xor(su, 8);
          float fc = __expf(mrow[mt][rr] - mn);
          lrow[mt][rr] = lrow[mt][rr] * fc + su;
          mrow[mt][rr] = mn;
          fac[mt][rr] = fc;
          unsigned short* pw = pw0 + (mt * 16 + g * 4 + rr) * 72;
          pw[r16] = f2bf(p0);
          pw[16 + r16] = f2bf(p1);
          pw[32 + r16] = f2bf(p2);
          pw[48 + r16] = f2bf(p3);
        }
      }
      for (int mt = 0; mt < 2; ++mt)
        for (int dt = 0; dt < 4; ++dt)
          for (int rr = 0; rr < 4; ++rr) accd[mt][dt][rr] *= fac[mt][rr];

      for (int kc = 0; kc < 2; ++kc) {
        s16x8 pa[2];
        for (int mt = 0; mt < 2; ++mt)
          pa[mt] = *(const s16x8*)((const char*)pw0 + (mt * 16 + r16) * 144 + kc * 64 + g * 16);
        for (int dt = 0; dt < 4; ++dt) {
          int row = dt * 16 + r16;
          int ch = (kc * 4 + g) ^ (row & 7);
          s16x8 bv = *(const s16x8*)(Vc + row * 128 + ch * 16);
          for (int mt = 0; mt < 2; ++mt)
            accd[mt][dt] = mfma16(pa[mt], bv, accd[mt][dt]);
        }
      }
    }
    cur ^= 1;
  }

  int b = bh >> 4, h = bh & (HH - 1);
  for (int mt = 0; mt < 2; ++mt) {
    for (int dt = 0; dt < 4; ++dt) {
      for (int rr = 0; rr < 4; ++rr) {
        int rowq = qw0 + mt * 16 + g * 4 + rr;
        float val = accd[mt][dt][rr] / lrow[mt][rr];
        ctx[(((size_t)b * SS + rowq) * HH + h) * DK + dt * 16 + r16] = f2bf(val);
      }
    }
  }
#undef STAGE_KV
}

extern "C" void kernel_launch(void* const* d_in, const int* in_sizes, int n_in,
                              void* d_out, int out_size, void* d_ws, size_t ws_size,
                              hipStream_t stream) {
  const float* q = (const float*)d_in[0];
  const float* k = (const float*)d_in[1];
  const float* v = (const float*)d_in[2];
  // d_in[3] = mask: exact causal tril, implemented in-kernel
  const float* Wq = (const float*)d_in[4];
  const float* bq = (const float*)d_in[5];
  const float* Wk = (const float*)d_in[6];
  const float* bk = (const float*)d_in[7];
  const float* Wv = (const float*)d_in[8];
  const float* bv = (const float*)d_in[9];
  const float* Wo = (const float*)d_in[10];
  const float* bo = (const float*)d_in[11];

  // Workspace layout (56 MB):
  //   [ 0, 8)  qb  -> reused as ctx    [ 8,16) kb    [16,24) vb -> reused as VhT
  //   [24,26) WqT  [26,28) WkT  [28,30) WvT  [30,32) WoT
  //   [32,40) Qh   [40,48) Kh   [48,56) Vh
  char* ws = (char*)d_ws;
  const size_t MB = 1ull << 20;
  unsigned short* qb = (unsigned short*)(ws + 0 * MB);
  unsigned short* kb = (unsigned short*)(ws + 8 * MB);
  unsigned short* vb = (unsigned short*)(ws + 16 * MB);
  unsigned short* WqT = (unsigned short*)(ws + 24 * MB);
  unsigned short* WkT = (unsigned short*)(ws + 26 * MB);
  unsigned short* WvT = (unsigned short*)(ws + 28 * MB);
  unsigned short* WoT = (unsigned short*)(ws + 30 * MB);
  unsigned short* Qh = (unsigned short*)(ws + 32 * MB);
  unsigned short* Kh = (unsigned short*)(ws + 40 * MB);
  unsigned short* Vh = (unsigned short*)(ws + 48 * MB);
  unsigned short* VhT = (unsigned short*)(ws + 16 * MB);  // reuse vb
  unsigned short* ctx = (unsigned short*)(ws + 0 * MB);   // reuse qb

  const int n4 = BB * SS * DD / 4;

  cvt_kernel<<<n4 / 256, 256, 0, stream>>>(q, qb, n4);
  cvt_kernel<<<n4 / 256, 256, 0, stream>>>(k, kb, n4);
  cvt_kernel<<<n4 / 256, 256, 0, stream>>>(v, vb, n4);

  dim3 tb(32, 8);
  transpose_w_kernel<<<dim3(32, 32), tb, 0, stream>>>(Wq, WqT, 0.125f);  // fold 1/sqrt(DK)
  transpose_w_kernel<<<dim3(32, 32), tb, 0, stream>>>(Wk, WkT, 1.0f);
  transpose_w_kernel<<<dim3(32, 32), tb, 0, stream>>>(Wv, WvT, 1.0f);
  transpose_w_kernel<<<dim3(32, 32), tb, 0, stream>>>(Wo, WoT, 1.0f);

  gemm_proj_kernel<<<dim3(8, 32), 256, 0, stream>>>(qb, WqT, bq, 0.125f, Qh);
  gemm_proj_kernel<<<dim3(8, 32), 256, 0, stream>>>(kb, WkT, bk, 1.0f, Kh);
  gemm_proj_kernel<<<dim3(8, 32), 256, 0, stream>>>(vb, WvT, bv, 1.0f, Vh);

  transpose_v_kernel<<<dim3(SS / 32, DK / 32, BB * HH), tb, 0, stream>>>(Vh, VhT);

  attn_kernel<<<dim3(SS / 128, BB * HH), 256, 0, stream>>>(Qh, Kh, VhT, ctx);

  gemm_out_kernel<<<dim3(16, 32), 256, 0, stream>>>(ctx, WoT, bo, (float*)d_out);
}

// Round 4
// 176.237 us; speedup vs baseline: 1.6935x; 1.4955x over previous
//
#include <hip/hip_runtime.h>
#include <stdint.h>

// Problem constants
#define BB 2
#define SS 2048
#define DD 1024
#define HH 16
#define DK 64

typedef short s16x8 __attribute__((ext_vector_type(8)));
typedef float f32x4 __attribute__((ext_vector_type(4)));
typedef unsigned short u16x4 __attribute__((ext_vector_type(4)));
typedef unsigned int u32x4 __attribute__((ext_vector_type(4)));

static __device__ __forceinline__ unsigned short f2bf(float f) {
  unsigned int u = __builtin_bit_cast(unsigned int, f);
  u = (u + 0x7fffu + ((u >> 16) & 1u)) >> 16;
  return (unsigned short)u;
}

static __device__ __forceinline__ unsigned int pack2bf(float lo, float hi) {
  return ((unsigned int)f2bf(hi) << 16) | (unsigned int)f2bf(lo);
}

static __device__ __forceinline__ f32x4 mfma16(s16x8 a, s16x8 b, f32x4 c) {
  return __builtin_amdgcn_mfma_f32_16x16x32_bf16(a, b, c, 0, 0, 0);
}

static __device__ __forceinline__ void gload_lds16(const void* g, void* l) {
  __builtin_amdgcn_global_load_lds(
      (const __attribute__((address_space(1))) unsigned int*)g,
      (__attribute__((address_space(3))) unsigned int*)l, 16, 0, 0);
}

// ---------------- fp32 -> bf16 elementwise convert (vectorized) ----------------
__global__ __launch_bounds__(256) void cvt_kernel(const float* __restrict__ in,
                                                  unsigned short* __restrict__ out,
                                                  int n4) {
  int i = blockIdx.x * 256 + threadIdx.x;
  if (i < n4) {
    f32x4 v = ((const f32x4*)in)[i];
    u16x4 o;
    o.x = f2bf(v.x); o.y = f2bf(v.y); o.z = f2bf(v.z); o.w = f2bf(v.w);
    ((u16x4*)out)[i] = o;
  }
}

// ---------------- W [K][N] fp32 -> WT [N][K] bf16 (with scale) ----------------
__global__ __launch_bounds__(256) void transpose_w_kernel(const float* __restrict__ W,
                                                          unsigned short* __restrict__ WT,
                                                          float scale) {
  __shared__ float t[32][33];
  int n0 = blockIdx.x * 32, k0 = blockIdx.y * 32;
  int tx = threadIdx.x, ty = threadIdx.y;
  for (int i = 0; i < 4; ++i)
    t[ty + 8 * i][tx] = W[(size_t)(k0 + ty + 8 * i) * DD + n0 + tx];
  __syncthreads();
  for (int i = 0; i < 4; ++i)
    WT[(size_t)(n0 + ty + 8 * i) * DD + k0 + tx] = f2bf(t[tx][ty + 8 * i] * scale);
}

// ---------------- V [bh][S][DK] bf16 -> VT [bh][DK][S] bf16 ----------------
__global__ __launch_bounds__(256) void transpose_v_kernel(const unsigned short* __restrict__ V,
                                                          unsigned short* __restrict__ VT) {
  __shared__ unsigned short t[32][33];
  int s0 = blockIdx.x * 32, d0 = blockIdx.y * 32, bh = blockIdx.z;
  int tx = threadIdx.x, ty = threadIdx.y;
  const unsigned short* Vb = V + (size_t)bh * SS * DK;
  unsigned short* Tb = VT + (size_t)bh * DK * SS;
  for (int i = 0; i < 4; ++i)
    t[ty + 8 * i][tx] = Vb[(size_t)(s0 + ty + 8 * i) * DK + d0 + tx];
  __syncthreads();
  for (int i = 0; i < 4; ++i)
    Tb[(size_t)(d0 + ty + 8 * i) * SS + s0 + tx] = t[tx][ty + 8 * i];
}

// ---------------- fused QKV projection GEMM ----------------
// grid (8, 96): blockIdx.y>>5 selects {Q,K,V}; (blockIdx.y&31)*128 = m0
__global__ __launch_bounds__(256) void gemm_qkv_kernel(
    const unsigned short* __restrict__ qb, const unsigned short* __restrict__ kb,
    const unsigned short* __restrict__ vb, const unsigned short* __restrict__ WqT,
    const unsigned short* __restrict__ WkT, const unsigned short* __restrict__ WvT,
    const float* __restrict__ bq, const float* __restrict__ bk,
    const float* __restrict__ bv, unsigned short* __restrict__ Qh,
    unsigned short* __restrict__ Kh, unsigned short* __restrict__ Vh) {
  const int K = DD;
  __shared__ __align__(16) unsigned short Alds[128 * 32];
  __shared__ __align__(16) unsigned short Blds[128 * 32];
  int tid = threadIdx.x;
  int lane = tid & 63, wave = tid >> 6;
  int g = lane >> 4, r16 = lane & 15;
  int seg = blockIdx.y >> 5;
  int m0 = (blockIdx.y & 31) * 128, n0 = blockIdx.x * 128;
  int wm = (wave >> 1) * 64, wn = (wave & 1) * 64;

  const unsigned short* A = (seg == 0) ? qb : ((seg == 1) ? kb : vb);
  const unsigned short* BT = (seg == 0) ? WqT : ((seg == 1) ? WkT : WvT);
  const float* bias = (seg == 0) ? bq : ((seg == 1) ? bk : bv);
  unsigned short* outh = (seg == 0) ? Qh : ((seg == 1) ? Kh : Vh);
  float bsc = (seg == 0) ? 0.125f : 1.0f;

  f32x4 acc[4][4] = {};

  int c0 = tid, c1 = tid + 256;
  int arow0 = c0 >> 2, arow1 = c1 >> 2;
  int as0 = (c0 & 3) ^ ((arow0 >> 1) & 3);
  int as1 = (c1 & 3) ^ ((arow1 >> 1) & 3);

  for (int k0 = 0; k0 < K; k0 += 32) {
    __syncthreads();
    gload_lds16((const char*)(A + (size_t)(m0 + arow0) * K + k0) + as0 * 16,
                (char*)Alds + wave * 1024);
    gload_lds16((const char*)(A + (size_t)(m0 + arow1) * K + k0) + as1 * 16,
                (char*)Alds + wave * 1024 + 4096);
    gload_lds16((const char*)(BT + (size_t)(n0 + arow0) * K + k0) + as0 * 16,
                (char*)Blds + wave * 1024);
    gload_lds16((const char*)(BT + (size_t)(n0 + arow1) * K + k0) + as1 * 16,
                (char*)Blds + wave * 1024 + 4096);
    __syncthreads();

    s16x8 af[4], bfr[4];
#pragma unroll
    for (int mt = 0; mt < 4; ++mt) {
      int row = wm + mt * 16 + r16;
      int ch = g ^ ((row >> 1) & 3);
      af[mt] = *(const s16x8*)((const char*)Alds + row * 64 + ch * 16);
    }
#pragma unroll
    for (int nt = 0; nt < 4; ++nt) {
      int row = wn + nt * 16 + r16;
      int ch = g ^ ((row >> 1) & 3);
      bfr[nt] = *(const s16x8*)((const char*)Blds + row * 64 + ch * 16);
    }
#pragma unroll
    for (int mt = 0; mt < 4; ++mt)
#pragma unroll
      for (int nt = 0; nt < 4; ++nt)
        acc[mt][nt] = mfma16(af[mt], bfr[nt], acc[mt][nt]);
  }

#pragma unroll
  for (int nt = 0; nt < 4; ++nt) {
    int col = n0 + wn + nt * 16 + r16;
    int h = col >> 6, dk = col & (DK - 1);
    float bvv = bias[col] * bsc;
#pragma unroll
    for (int mt = 0; mt < 4; ++mt) {
#pragma unroll
      for (int rr = 0; rr < 4; ++rr) {
        int rowg = m0 + wm + mt * 16 + g * 4 + rr;
        int bb = rowg >> 11, s = rowg & (SS - 1);
        float val = acc[mt][nt][rr] + bvv;
        outh[(((size_t)bb * HH + h) * SS + s) * DK + dk] = f2bf(val);
      }
    }
  }
}

// ---------------- output GEMM: C[4096][1024] = ctx @ WoT^T + bo (fp32), 128x64 tile ----------------
__global__ __launch_bounds__(256) void gemm_out_kernel(const unsigned short* __restrict__ A,
                                                       const unsigned short* __restrict__ BT,
                                                       const float* __restrict__ bias,
                                                       float* __restrict__ out) {
  const int K = DD;
  __shared__ __align__(16) unsigned short Alds[128 * 32];
  __shared__ __align__(16) unsigned short Blds[64 * 32];
  int tid = threadIdx.x;
  int lane = tid & 63, wave = tid >> 6;
  int g = lane >> 4, r16 = lane & 15;
  int m0 = blockIdx.y * 128, n0 = blockIdx.x * 64;
  int wm = (wave >> 1) * 64, wn = (wave & 1) * 32;

  f32x4 acc[4][2] = {};

  int c0 = tid, c1 = tid + 256;
  int arow0 = c0 >> 2, arow1 = c1 >> 2;
  int as0 = (c0 & 3) ^ ((arow0 >> 1) & 3);
  int as1 = (c1 & 3) ^ ((arow1 >> 1) & 3);

  for (int k0 = 0; k0 < K; k0 += 32) {
    __syncthreads();
    gload_lds16((const char*)(A + (size_t)(m0 + arow0) * K + k0) + as0 * 16,
                (char*)Alds + wave * 1024);
    gload_lds16((const char*)(A + (size_t)(m0 + arow1) * K + k0) + as1 * 16,
                (char*)Alds + wave * 1024 + 4096);
    gload_lds16((const char*)(BT + (size_t)(n0 + arow0) * K + k0) + as0 * 16,
                (char*)Blds + wave * 1024);
    __syncthreads();

    s16x8 af[4], bfr[2];
#pragma unroll
    for (int mt = 0; mt < 4; ++mt) {
      int row = wm + mt * 16 + r16;
      int ch = g ^ ((row >> 1) & 3);
      af[mt] = *(const s16x8*)((const char*)Alds + row * 64 + ch * 16);
    }
#pragma unroll
    for (int nt = 0; nt < 2; ++nt) {
      int row = wn + nt * 16 + r16;
      int ch = g ^ ((row >> 1) & 3);
      bfr[nt] = *(const s16x8*)((const char*)Blds + row * 64 + ch * 16);
    }
#pragma unroll
    for (int mt = 0; mt < 4; ++mt)
#pragma unroll
      for (int nt = 0; nt < 2; ++nt)
        acc[mt][nt] = mfma16(af[mt], bfr[nt], acc[mt][nt]);
  }

#pragma unroll
  for (int nt = 0; nt < 2; ++nt) {
    int col = n0 + wn + nt * 16 + r16;
    float bvv = bias[col];
#pragma unroll
    for (int mt = 0; mt < 4; ++mt) {
#pragma unroll
      for (int rr = 0; rr < 4; ++rr) {
        int rowg = m0 + wm + mt * 16 + g * 4 + rr;
        out[(size_t)rowg * DD + col] = acc[mt][nt][rr] + bvv;
      }
    }
  }
}

// ---------------- causal flash attention, fully in-register softmax ----------------
// Swapped QK^T: S^T = mfma(A=K-rows(permuted), B=Q) -> lane col = q.
// Key permutation: subtile nt covers key(i) = 8*(i>>2) + 4*(nt&1) + (i&3) (+32*(nt>>1)),
// so each lane ends up holding keys 8g..8g+7 of each 32-key chunk -> PV B-operand
// (P^T) is lane-local (zero cross-lane exchange).
// Swapped PV: O^T = mfma(A=V^T-rows, B=P^T) -> lane col = q (stats stay lane-aligned).
__global__ __launch_bounds__(256) void attn_kernel(const unsigned short* __restrict__ Qh,
                                                   const unsigned short* __restrict__ Kh,
                                                   const unsigned short* __restrict__ VhT,
                                                   unsigned short* __restrict__ ctx) {
  __shared__ __align__(16) unsigned short Klds[2][64 * 64];  // [key][dk], swz s=(r&3)|(((r>>3)&1)<<2)
  __shared__ __align__(16) unsigned short Vlds[2][64 * 64];  // [d][key], swz s=r&7

  int tid = threadIdx.x;
  int lane = tid & 63, wave = tid >> 6;
  int g = lane >> 4, r16 = lane & 15;
  int q0 = (int)(gridDim.x - 1 - blockIdx.x) * 128;  // big blocks dispatch first
  int bh = blockIdx.y;
  int qw0 = q0 + wave * 32;

  const unsigned short* Qb = Qh + (size_t)bh * SS * DK;
  const char* Kb = (const char*)(Kh + (size_t)bh * SS * DK);
  const char* Vb = (const char*)(VhT + (size_t)bh * DK * SS);

  // Q as B-operand: lane (q-col = r16, group g) holds Q[qw0+mt*16+r16][kc*32+8g..+7]
  s16x8 aq[2][2];
#pragma unroll
  for (int mt = 0; mt < 2; ++mt)
#pragma unroll
    for (int kc = 0; kc < 2; ++kc)
      aq[mt][kc] = *(const s16x8*)(Qb + (size_t)(qw0 + mt * 16 + r16) * DK + kc * 32 + g * 8);

  f32x4 accd[2][4] = {};  // [mt][dsub]: O^T[d=dsub*16+4g+rr][q=qw0+mt*16+r16]
  float mrow[2] = {-INFINITY, -INFINITY};
  float lrow[2] = {0.0f, 0.0f};

  // K-frag read constants: row(nt) = 8a + b + 4*(nt&1) + 32*(nt>>1); swizzle sk = b + 4*(a&1)
  int a_ = r16 >> 2, b_ = r16 & 3;
  int rbase = 8 * a_ + b_;
  int sk = b_ + 4 * (a_ & 1);

  // staging: 512 chunks of 16B per tile; chunk c -> row=c>>3, col=c&7; pre-swizzled source
  int c0 = tid, c1 = tid + 256;
  int row0 = c0 >> 3, row1 = c1 >> 3;
  int skst0 = ((row0 & 3) | (((row0 >> 3) & 1) << 2));
  int skst1 = ((row1 & 3) | (((row1 >> 3) & 1) << 2));
  int kc0 = (c0 & 7) ^ skst0, kc1 = (c1 & 7) ^ skst1;
  int vc0 = (c0 & 7) ^ (row0 & 7), vc1 = (c1 & 7) ^ (row1 & 7);

#define STAGE_KV(buf, kv0)                                                   \
  do {                                                                       \
    gload_lds16(Kb + ((size_t)((kv0) + row0) * 128) + kc0 * 16,              \
                (char*)Klds[buf] + wave * 1024);                             \
    gload_lds16(Kb + ((size_t)((kv0) + row1) * 128) + kc1 * 16,              \
                (char*)Klds[buf] + wave * 1024 + 4096);                      \
    gload_lds16(Vb + ((size_t)row0 * SS + (kv0)) * 2 + vc0 * 16,             \
                (char*)Vlds[buf] + wave * 1024);                             \
    gload_lds16(Vb + ((size_t)row1 * SS + (kv0)) * 2 + vc1 * 16,             \
                (char*)Vlds[buf] + wave * 1024 + 4096);                      \
  } while (0)

  int ntiles = q0 / 64 + 2;
  STAGE_KV(0, 0);
  int cur = 0;

  for (int t = 0; t < ntiles; ++t) {
    int kv0 = t * 64;
    __syncthreads();  // implicit vmcnt(0): buf[cur] staged, buf[cur^1] consumed
    if (t + 1 < ntiles) STAGE_KV(cur ^ 1, kv0 + 64);

    if (kv0 <= qw0 + 31) {
      const char* Kc = (const char*)Klds[cur];
      const char* Vc = (const char*)Vlds[cur];

      // ---- QK^T (swapped): sf[mt][nt][rr] = score(key = kv0+8g+4*(nt&1)+rr+32*(nt>>1),
      //                                            q = qw0+mt*16+r16)
      f32x4 sf[2][4] = {};
      __builtin_amdgcn_s_setprio(1);
#pragma unroll
      for (int kc = 0; kc < 2; ++kc) {
        s16x8 bk[4];
#pragma unroll
        for (int nt = 0; nt < 4; ++nt) {
          int row = rbase + 4 * (nt & 1) + 32 * (nt >> 1);
          int ch = (kc * 4 + g) ^ sk;
          bk[nt] = *(const s16x8*)(Kc + row * 128 + ch * 16);
        }
#pragma unroll
        for (int mt = 0; mt < 2; ++mt)
#pragma unroll
          for (int nt = 0; nt < 4; ++nt)
            sf[mt][nt] = mfma16(bk[nt], aq[mt][kc], sf[mt][nt]);
      }
      __builtin_amdgcn_s_setprio(0);

      bool domask = (kv0 + 63 > qw0);
      unsigned int pk[2][2][4];  // [mt][chunk][dword]
#pragma unroll
      for (int mt = 0; mt < 2; ++mt) {
        int qg = qw0 + mt * 16 + r16;
        // mask + tile max
        float tmax = -INFINITY;
#pragma unroll
        for (int nt = 0; nt < 4; ++nt) {
          int kbase = kv0 + 8 * g + 4 * (nt & 1) + 32 * (nt >> 1);
#pragma unroll
          for (int rr = 0; rr < 4; ++rr) {
            float sc = sf[mt][nt][rr];
            if (domask && (kbase + rr > qg)) sc = -INFINITY;
            sf[mt][nt][rr] = sc;
            tmax = fmaxf(tmax, sc);
          }
        }
        tmax = fmaxf(tmax, __shfl_xor(tmax, 16));
        tmax = fmaxf(tmax, __shfl_xor(tmax, 32));
        float mn = fmaxf(mrow[mt], tmax);
        float su = 0.0f;
        float pf[4][4];
#pragma unroll
        for (int nt = 0; nt < 4; ++nt)
#pragma unroll
          for (int rr = 0; rr < 4; ++rr) {
            float p = __expf(sf[mt][nt][rr] - mn);
            pf[nt][rr] = p;
            su += p;
          }
        su += __shfl_xor(su, 16);
        su += __shfl_xor(su, 32);
        float fc = __expf(mrow[mt] - mn);
        lrow[mt] = lrow[mt] * fc + su;
        mrow[mt] = mn;
#pragma unroll
        for (int c = 0; c < 2; ++c) {
          pk[mt][c][0] = pack2bf(pf[2 * c][0], pf[2 * c][1]);
          pk[mt][c][1] = pack2bf(pf[2 * c][2], pf[2 * c][3]);
          pk[mt][c][2] = pack2bf(pf[2 * c + 1][0], pf[2 * c + 1][1]);
          pk[mt][c][3] = pack2bf(pf[2 * c + 1][2], pf[2 * c + 1][3]);
        }
#pragma unroll
        for (int dsub = 0; dsub < 4; ++dsub)
#pragma unroll
          for (int rr = 0; rr < 4; ++rr) accd[mt][dsub][rr] *= fc;
      }

      // ---- PV (swapped): accd[mt][dsub] += mfma(A=V^T rows, B=P^T)
      __builtin_amdgcn_s_setprio(1);
#pragma unroll
      for (int c = 0; c < 2; ++c) {
        s16x8 pb0 = __builtin_bit_cast(s16x8, *(u32x4*)pk[0][c]);
        s16x8 pb1 = __builtin_bit_cast(s16x8, *(u32x4*)pk[1][c]);
#pragma unroll
        for (int dsub = 0; dsub < 4; ++dsub) {
          int row = dsub * 16 + r16;
          int ch = (c * 4 + g) ^ (row & 7);
          s16x8 av = *(const s16x8*)(Vc + row * 128 + ch * 16);
          accd[0][dsub] = mfma16(av, pb0, accd[0][dsub]);
          accd[1][dsub] = mfma16(av, pb1, accd[1][dsub]);
        }
      }
      __builtin_amdgcn_s_setprio(0);
    }
    cur ^= 1;
  }

  int b = bh >> 4, h = bh & (HH - 1);
#pragma unroll
  for (int mt = 0; mt < 2; ++mt) {
    int srow = qw0 + mt * 16 + r16;
    float inv = 1.0f / lrow[mt];
#pragma unroll
    for (int dsub = 0; dsub < 4; ++dsub) {
      int d0 = dsub * 16 + 4 * g;
      u16x4 o;
#pragma unroll
      for (int rr = 0; rr < 4; ++rr) o[rr] = f2bf(accd[mt][dsub][rr] * inv);
      *(u16x4*)&ctx[(((size_t)b * SS + srow) * HH + h) * DK + d0] = o;
    }
  }
#undef STAGE_KV
}

extern "C" void kernel_launch(void* const* d_in, const int* in_sizes, int n_in,
                              void* d_out, int out_size, void* d_ws, size_t ws_size,
                              hipStream_t stream) {
  const float* q = (const float*)d_in[0];
  const float* k = (const float*)d_in[1];
  const float* v = (const float*)d_in[2];
  // d_in[3] = mask: exact causal tril, implemented in-kernel
  const float* Wq = (const float*)d_in[4];
  const float* bq = (const float*)d_in[5];
  const float* Wk = (const float*)d_in[6];
  const float* bk = (const float*)d_in[7];
  const float* Wv = (const float*)d_in[8];
  const float* bv = (const float*)d_in[9];
  const float* Wo = (const float*)d_in[10];
  const float* bo = (const float*)d_in[11];

  // Workspace layout (56 MB):
  //   [ 0, 8)  qb  -> reused as ctx    [ 8,16) kb    [16,24) vb -> reused as VhT
  //   [24,26) WqT  [26,28) WkT  [28,30) WvT  [30,32) WoT
  //   [32,40) Qh   [40,48) Kh   [48,56) Vh
  char* ws = (char*)d_ws;
  const size_t MB = 1ull << 20;
  unsigned short* qb = (unsigned short*)(ws + 0 * MB);
  unsigned short* kb = (unsigned short*)(ws + 8 * MB);
  unsigned short* vb = (unsigned short*)(ws + 16 * MB);
  unsigned short* WqT = (unsigned short*)(ws + 24 * MB);
  unsigned short* WkT = (unsigned short*)(ws + 26 * MB);
  unsigned short* WvT = (unsigned short*)(ws + 28 * MB);
  unsigned short* WoT = (unsigned short*)(ws + 30 * MB);
  unsigned short* Qh = (unsigned short*)(ws + 32 * MB);
  unsigned short* Kh = (unsigned short*)(ws + 40 * MB);
  unsigned short* Vh = (unsigned short*)(ws + 48 * MB);
  unsigned short* VhT = (unsigned short*)(ws + 16 * MB);  // reuse vb
  unsigned short* ctx = (unsigned short*)(ws + 0 * MB);   // reuse qb

  const int n4 = BB * SS * DD / 4;

  cvt_kernel<<<n4 / 256, 256, 0, stream>>>(q, qb, n4);
  cvt_kernel<<<n4 / 256, 256, 0, stream>>>(k, kb, n4);
  cvt_kernel<<<n4 / 256, 256, 0, stream>>>(v, vb, n4);

  dim3 tb(32, 8);
  transpose_w_kernel<<<dim3(32, 32), tb, 0, stream>>>(Wq, WqT, 0.125f);  // fold 1/sqrt(DK)
  transpose_w_kernel<<<dim3(32, 32), tb, 0, stream>>>(Wk, WkT, 1.0f);
  transpose_w_kernel<<<dim3(32, 32), tb, 0, stream>>>(Wv, WvT, 1.0f);
  transpose_w_kernel<<<dim3(32, 32), tb, 0, stream>>>(Wo, WoT, 1.0f);

  gemm_qkv_kernel<<<dim3(8, 96), 256, 0, stream>>>(qb, kb, vb, WqT, WkT, WvT,
                                                   bq, bk, bv, Qh, Kh, Vh);

  transpose_v_kernel<<<dim3(SS / 32, DK / 32, BB * HH), tb, 0, stream>>>(Vh, VhT);

  attn_kernel<<<dim3(SS / 128, BB * HH), 256, 0, stream>>>(Qh, Kh, VhT, ctx);

  gemm_out_kernel<<<dim3(16, 32), 256, 0, stream>>>(ctx, WoT, bo, (float*)d_out);
}

// Round 5
// 144.985 us; speedup vs baseline: 2.0586x; 1.2156x over previous
//
#include <hip/hip_runtime.h>
#include <stdint.h>

// Problem constants
#define BB 2
#define SS 2048
#define DD 1024
#define HH 16
#define DK 64

// 0.125 (1/sqrt(DK)) * log2(e): QK^T scores land in log2 domain -> exp2 softmax
#define QSCALE 0.1803368801111204f

typedef short s16x8 __attribute__((ext_vector_type(8)));
typedef float f32x4 __attribute__((ext_vector_type(4)));
typedef unsigned short u16x4 __attribute__((ext_vector_type(4)));
typedef unsigned int u32x4 __attribute__((ext_vector_type(4)));

static __device__ __forceinline__ unsigned short f2bf(float f) {
  unsigned int u = __builtin_bit_cast(unsigned int, f);
  u = (u + 0x7fffu + ((u >> 16) & 1u)) >> 16;
  return (unsigned short)u;
}

// v_cvt_pk_bf16_f32: lo -> low 16, hi -> high 16 (RTNE)
static __device__ __forceinline__ unsigned int cvtpk(float lo, float hi) {
  unsigned int r;
  asm("v_cvt_pk_bf16_f32 %0, %1, %2" : "=v"(r) : "v"(lo), "v"(hi));
  return r;
}

static __device__ __forceinline__ f32x4 mfma16(s16x8 a, s16x8 b, f32x4 c) {
  return __builtin_amdgcn_mfma_f32_16x16x32_bf16(a, b, c, 0, 0, 0);
}

static __device__ __forceinline__ void gload_lds16(const void* g, void* l) {
  __builtin_amdgcn_global_load_lds(
      (const __attribute__((address_space(1))) unsigned int*)g,
      (__attribute__((address_space(3))) unsigned int*)l, 16, 0, 0);
}

// ---------------- fp32 -> bf16 convert, all 3 tensors in one launch ----------------
__global__ __launch_bounds__(256) void cvt3_kernel(const float* __restrict__ q,
                                                   const float* __restrict__ k,
                                                   const float* __restrict__ v,
                                                   unsigned short* __restrict__ qb,
                                                   unsigned short* __restrict__ kb,
                                                   unsigned short* __restrict__ vb) {
  int sel = blockIdx.y;
  const float* in = (sel == 0) ? q : ((sel == 1) ? k : v);
  unsigned short* out = (sel == 0) ? qb : ((sel == 1) ? kb : vb);
  int i = blockIdx.x * 256 + threadIdx.x;
  f32x4 vv = ((const f32x4*)in)[i];
  u16x4 o;
  o.x = f2bf(vv.x); o.y = f2bf(vv.y); o.z = f2bf(vv.z); o.w = f2bf(vv.w);
  ((u16x4*)out)[i] = o;
}

// ---------------- all 4 W [K][N] fp32 -> WT [N][K] bf16 in one launch ----------------
__global__ __launch_bounds__(256) void transpose_w4_kernel(const float* __restrict__ Wq,
                                                           const float* __restrict__ Wk,
                                                           const float* __restrict__ Wv,
                                                           const float* __restrict__ Wo,
                                                           unsigned short* __restrict__ WTbase) {
  __shared__ float t[32][33];
  int z = blockIdx.z;
  const float* W = (z == 0) ? Wq : ((z == 1) ? Wk : ((z == 2) ? Wv : Wo));
  float scale = (z == 0) ? QSCALE : 1.0f;
  unsigned short* WT = WTbase + (size_t)z * DD * DD;
  int n0 = blockIdx.x * 32, k0 = blockIdx.y * 32;
  int tx = threadIdx.x, ty = threadIdx.y;
  for (int i = 0; i < 4; ++i)
    t[ty + 8 * i][tx] = W[(size_t)(k0 + ty + 8 * i) * DD + n0 + tx];
  __syncthreads();
  for (int i = 0; i < 4; ++i)
    WT[(size_t)(n0 + ty + 8 * i) * DD + k0 + tx] = f2bf(t[tx][ty + 8 * i] * scale);
}

// ---------------- V [bh][S][DK] bf16 -> VT [bh][DK][S] bf16 ----------------
__global__ __launch_bounds__(256) void transpose_v_kernel(const unsigned short* __restrict__ V,
                                                          unsigned short* __restrict__ VT) {
  __shared__ unsigned short t[32][33];
  int s0 = blockIdx.x * 32, d0 = blockIdx.y * 32, bh = blockIdx.z;
  int tx = threadIdx.x, ty = threadIdx.y;
  const unsigned short* Vb = V + (size_t)bh * SS * DK;
  unsigned short* Tb = VT + (size_t)bh * DK * SS;
  for (int i = 0; i < 4; ++i)
    t[ty + 8 * i][tx] = Vb[(size_t)(s0 + ty + 8 * i) * DK + d0 + tx];
  __syncthreads();
  for (int i = 0; i < 4; ++i)
    Tb[(size_t)(d0 + ty + 8 * i) * SS + s0 + tx] = t[tx][ty + 8 * i];
}

// ---------------- fused QKV projection GEMM ----------------
// grid (8, 96): blockIdx.y>>5 selects {Q,K,V}; (blockIdx.y&31)*128 = m0
__global__ __launch_bounds__(256) void gemm_qkv_kernel(
    const unsigned short* __restrict__ qb, const unsigned short* __restrict__ kb,
    const unsigned short* __restrict__ vb, const unsigned short* __restrict__ WTbase,
    const float* __restrict__ bq, const float* __restrict__ bk,
    const float* __restrict__ bv, unsigned short* __restrict__ Qh,
    unsigned short* __restrict__ Kh, unsigned short* __restrict__ Vh) {
  const int K = DD;
  __shared__ __align__(16) unsigned short Alds[128 * 32];
  __shared__ __align__(16) unsigned short Blds[128 * 32];
  int tid = threadIdx.x;
  int lane = tid & 63, wave = tid >> 6;
  int g = lane >> 4, r16 = lane & 15;
  int seg = blockIdx.y >> 5;
  int m0 = (blockIdx.y & 31) * 128, n0 = blockIdx.x * 128;
  int wm = (wave >> 1) * 64, wn = (wave & 1) * 64;

  const unsigned short* A = (seg == 0) ? qb : ((seg == 1) ? kb : vb);
  const unsigned short* BT = WTbase + (size_t)seg * DD * DD;
  const float* bias = (seg == 0) ? bq : ((seg == 1) ? bk : bv);
  unsigned short* outh = (seg == 0) ? Qh : ((seg == 1) ? Kh : Vh);
  float bsc = (seg == 0) ? QSCALE : 1.0f;

  f32x4 acc[4][4] = {};

  int c0 = tid, c1 = tid + 256;
  int arow0 = c0 >> 2, arow1 = c1 >> 2;
  int as0 = (c0 & 3) ^ ((arow0 >> 1) & 3);
  int as1 = (c1 & 3) ^ ((arow1 >> 1) & 3);

  for (int k0 = 0; k0 < K; k0 += 32) {
    __syncthreads();
    gload_lds16((const char*)(A + (size_t)(m0 + arow0) * K + k0) + as0 * 16,
                (char*)Alds + wave * 1024);
    gload_lds16((const char*)(A + (size_t)(m0 + arow1) * K + k0) + as1 * 16,
                (char*)Alds + wave * 1024 + 4096);
    gload_lds16((const char*)(BT + (size_t)(n0 + arow0) * K + k0) + as0 * 16,
                (char*)Blds + wave * 1024);
    gload_lds16((const char*)(BT + (size_t)(n0 + arow1) * K + k0) + as1 * 16,
                (char*)Blds + wave * 1024 + 4096);
    __syncthreads();

    s16x8 af[4], bfr[4];
#pragma unroll
    for (int mt = 0; mt < 4; ++mt) {
      int row = wm + mt * 16 + r16;
      int ch = g ^ ((row >> 1) & 3);
      af[mt] = *(const s16x8*)((const char*)Alds + row * 64 + ch * 16);
    }
#pragma unroll
    for (int nt = 0; nt < 4; ++nt) {
      int row = wn + nt * 16 + r16;
      int ch = g ^ ((row >> 1) & 3);
      bfr[nt] = *(const s16x8*)((const char*)Blds + row * 64 + ch * 16);
    }
#pragma unroll
    for (int mt = 0; mt < 4; ++mt)
#pragma unroll
      for (int nt = 0; nt < 4; ++nt)
        acc[mt][nt] = mfma16(af[mt], bfr[nt], acc[mt][nt]);
  }

#pragma unroll
  for (int nt = 0; nt < 4; ++nt) {
    int col = n0 + wn + nt * 16 + r16;
    int h = col >> 6, dk = col & (DK - 1);
    float bvv = bias[col] * bsc;
#pragma unroll
    for (int mt = 0; mt < 4; ++mt) {
#pragma unroll
      for (int rr = 0; rr < 4; ++rr) {
        int rowg = m0 + wm + mt * 16 + g * 4 + rr;
        int bb = rowg >> 11, s = rowg & (SS - 1);
        float val = acc[mt][nt][rr] + bvv;
        outh[(((size_t)bb * HH + h) * SS + s) * DK + dk] = f2bf(val);
      }
    }
  }
}

// ---------------- output GEMM: C[4096][1024] = ctx @ WoT^T + bo (fp32), 128x64 tile ----------------
__global__ __launch_bounds__(256) void gemm_out_kernel(const unsigned short* __restrict__ A,
                                                       const unsigned short* __restrict__ BT,
                                                       const float* __restrict__ bias,
                                                       float* __restrict__ out) {
  const int K = DD;
  __shared__ __align__(16) unsigned short Alds[128 * 32];
  __shared__ __align__(16) unsigned short Blds[64 * 32];
  int tid = threadIdx.x;
  int lane = tid & 63, wave = tid >> 6;
  int g = lane >> 4, r16 = lane & 15;
  int m0 = blockIdx.y * 128, n0 = blockIdx.x * 64;
  int wm = (wave >> 1) * 64, wn = (wave & 1) * 32;

  f32x4 acc[4][2] = {};

  int c0 = tid, c1 = tid + 256;
  int arow0 = c0 >> 2, arow1 = c1 >> 2;
  int as0 = (c0 & 3) ^ ((arow0 >> 1) & 3);
  int as1 = (c1 & 3) ^ ((arow1 >> 1) & 3);

  for (int k0 = 0; k0 < K; k0 += 32) {
    __syncthreads();
    gload_lds16((const char*)(A + (size_t)(m0 + arow0) * K + k0) + as0 * 16,
                (char*)Alds + wave * 1024);
    gload_lds16((const char*)(A + (size_t)(m0 + arow1) * K + k0) + as1 * 16,
                (char*)Alds + wave * 1024 + 4096);
    gload_lds16((const char*)(BT + (size_t)(n0 + arow0) * K + k0) + as0 * 16,
                (char*)Blds + wave * 1024);
    __syncthreads();

    s16x8 af[4], bfr[2];
#pragma unroll
    for (int mt = 0; mt < 4; ++mt) {
      int row = wm + mt * 16 + r16;
      int ch = g ^ ((row >> 1) & 3);
      af[mt] = *(const s16x8*)((const char*)Alds + row * 64 + ch * 16);
    }
#pragma unroll
    for (int nt = 0; nt < 2; ++nt) {
      int row = wn + nt * 16 + r16;
      int ch = g ^ ((row >> 1) & 3);
      bfr[nt] = *(const s16x8*)((const char*)Blds + row * 64 + ch * 16);
    }
#pragma unroll
    for (int mt = 0; mt < 4; ++mt)
#pragma unroll
      for (int nt = 0; nt < 2; ++nt)
        acc[mt][nt] = mfma16(af[mt], bfr[nt], acc[mt][nt]);
  }

#pragma unroll
  for (int nt = 0; nt < 2; ++nt) {
    int col = n0 + wn + nt * 16 + r16;
    float bvv = bias[col];
#pragma unroll
    for (int mt = 0; mt < 4; ++mt) {
#pragma unroll
      for (int rr = 0; rr < 4; ++rr) {
        int rowg = m0 + wm + mt * 16 + g * 4 + rr;
        out[(size_t)rowg * DD + col] = acc[mt][nt][rr] + bvv;
      }
    }
  }
}

// ---------------- causal flash attention, QBLK=64, in-register softmax ----------------
// Swapped QK^T: S^T = mfma(A=K-rows(permuted), B=Q) -> lane col = q.
// Key perm: subtile nt covers key = 8g + 4*(nt&1) + rr + 32*(nt>>1) so each lane
// holds keys 8g..8g+7 of each 32-chunk -> PV B-operand (P^T) is lane-local.
// Scores arrive in log2 domain (log2e folded into Wq): softmax uses exp2.
__global__ __launch_bounds__(256) void attn_kernel(const unsigned short* __restrict__ Qh,
                                                   const unsigned short* __restrict__ Kh,
                                                   const unsigned short* __restrict__ VhT,
                                                   unsigned short* __restrict__ ctx) {
  __shared__ __align__(16) unsigned short Klds[2][64 * 64];  // [key][dk], swz (r&3)|(((r>>3)&1)<<2)
  __shared__ __align__(16) unsigned short Vlds[2][64 * 64];  // [d][key], swz r&7

  int tid = threadIdx.x;
  int lane = tid & 63, wave = tid >> 6;
  int g = lane >> 4, r16 = lane & 15;
  int q0 = (int)(gridDim.x - 1 - blockIdx.x) * 64;  // big blocks dispatch first
  int bh = blockIdx.y;
  int qw0 = q0 + wave * 16;

  const unsigned short* Qb = Qh + (size_t)bh * SS * DK;
  const char* Kb = (const char*)(Kh + (size_t)bh * SS * DK);
  const char* Vb = (const char*)(VhT + (size_t)bh * DK * SS);

  // Q as B-operand: lane holds Q[qw0+r16][kc*32+8g..+7]
  s16x8 aq[2];
#pragma unroll
  for (int kc = 0; kc < 2; ++kc)
    aq[kc] = *(const s16x8*)(Qb + (size_t)(qw0 + r16) * DK + kc * 32 + g * 8);

  f32x4 accd[4] = {};  // [dsub]: O^T[d=dsub*16+4g+rr][q=qw0+r16]
  float mrow = -INFINITY, lrow = 0.0f;

  // K-frag read constants: row(nt) = 8a + b + 4*(nt&1) + 32*(nt>>1); swizzle sk = b + 4*(a&1)
  int a_ = r16 >> 2, b_ = r16 & 3;
  int rbase = 8 * a_ + b_;
  int sk = b_ + 4 * (a_ & 1);

  // staging: 1024 chunks of 16B (K 512 + V 512); chunk c -> row=c>>3, col=c&7; pre-swz src
  int c0 = tid, c1 = tid + 256;
  int row0 = c0 >> 3, row1 = c1 >> 3;
  int skst0 = ((row0 & 3) | (((row0 >> 3) & 1) << 2));
  int skst1 = ((row1 & 3) | (((row1 >> 3) & 1) << 2));
  int kc0 = (c0 & 7) ^ skst0, kc1 = (c1 & 7) ^ skst1;
  int vc0 = (c0 & 7) ^ (row0 & 7), vc1 = (c1 & 7) ^ (row1 & 7);

#define STAGE_KV(buf, kv0)                                                   \
  do {                                                                       \
    gload_lds16(Kb + ((size_t)((kv0) + row0) * 128) + kc0 * 16,              \
                (char*)Klds[buf] + wave * 1024);                             \
    gload_lds16(Kb + ((size_t)((kv0) + row1) * 128) + kc1 * 16,              \
                (char*)Klds[buf] + wave * 1024 + 4096);                      \
    gload_lds16(Vb + ((size_t)row0 * SS + (kv0)) * 2 + vc0 * 16,             \
                (char*)Vlds[buf] + wave * 1024);                             \
    gload_lds16(Vb + ((size_t)row1 * SS + (kv0)) * 2 + vc1 * 16,             \
                (char*)Vlds[buf] + wave * 1024 + 4096);                      \
  } while (0)

  int ntiles = q0 / 64 + 1;
  STAGE_KV(0, 0);
  int cur = 0;

  for (int t = 0; t < ntiles; ++t) {
    int kv0 = t * 64;
    __syncthreads();  // implicit vmcnt(0): buf[cur] staged, buf[cur^1] consumed
    if (t + 1 < ntiles) STAGE_KV(cur ^ 1, kv0 + 64);

    const char* Kc = (const char*)Klds[cur];
    const char* Vc = (const char*)Vlds[cur];

    // ---- QK^T (swapped): sf[nt][rr] = S[key = kv0+8g+4(nt&1)+rr+32(nt>>1)][q = qw0+r16]
    f32x4 sf[4] = {};
    __builtin_amdgcn_s_setprio(1);
#pragma unroll
    for (int kc = 0; kc < 2; ++kc) {
      s16x8 bk[4];
#pragma unroll
      for (int nt = 0; nt < 4; ++nt) {
        int row = rbase + 4 * (nt & 1) + 32 * (nt >> 1);
        int ch = (kc * 4 + g) ^ sk;
        bk[nt] = *(const s16x8*)(Kc + row * 128 + ch * 16);
      }
#pragma unroll
      for (int nt = 0; nt < 4; ++nt)
        sf[nt] = mfma16(bk[nt], aq[kc], sf[nt]);
    }
    __builtin_amdgcn_s_setprio(0);

    // ---- mask (diagonal tiles only; wave-uniform branch)
    if (kv0 + 63 > qw0) {
      int thr = qw0 + r16 - kv0 - 8 * g;  // key offset limit
#pragma unroll
      for (int nt = 0; nt < 4; ++nt) {
        int koff = 4 * (nt & 1) + 32 * (nt >> 1);
#pragma unroll
        for (int rr = 0; rr < 4; ++rr)
          if (koff + rr > thr) sf[nt][rr] = -INFINITY;
      }
    }

    // ---- online softmax (log2 domain), lane-local + 2 shuffles per stat
    float tmax = -INFINITY;
#pragma unroll
    for (int nt = 0; nt < 4; ++nt)
#pragma unroll
      for (int rr = 0; rr < 4; ++rr) tmax = fmaxf(tmax, sf[nt][rr]);
    tmax = fmaxf(tmax, __shfl_xor(tmax, 16));
    tmax = fmaxf(tmax, __shfl_xor(tmax, 32));

    if (!__all(tmax <= mrow)) {  // exact defer: skip is numerically identical
      float mn = fmaxf(mrow, tmax);
      float fc = __builtin_amdgcn_exp2f(mrow - mn);
      lrow *= fc;
      mrow = mn;
#pragma unroll
      for (int dsub = 0; dsub < 4; ++dsub)
#pragma unroll
        for (int rr = 0; rr < 4; ++rr) accd[dsub][rr] *= fc;
    }

    float pf[4][4];
    float su = 0.0f;
#pragma unroll
    for (int nt = 0; nt < 4; ++nt)
#pragma unroll
      for (int rr = 0; rr < 4; ++rr) {
        float p = __builtin_amdgcn_exp2f(sf[nt][rr] - mrow);
        pf[nt][rr] = p;
        su += p;
      }
    su += __shfl_xor(su, 16);
    su += __shfl_xor(su, 32);
    lrow += su;

    // pack P^T fragments: chunk c holds keys c*32 + 8g..+7 in k-ascending order
    unsigned int pk[2][4];
#pragma unroll
    for (int c = 0; c < 2; ++c) {
      pk[c][0] = cvtpk(pf[2 * c][0], pf[2 * c][1]);
      pk[c][1] = cvtpk(pf[2 * c][2], pf[2 * c][3]);
      pk[c][2] = cvtpk(pf[2 * c + 1][0], pf[2 * c + 1][1]);
      pk[c][3] = cvtpk(pf[2 * c + 1][2], pf[2 * c + 1][3]);
    }

    // ---- PV (swapped): accd[dsub] += mfma(A=V^T rows, B=P^T)
    __builtin_amdgcn_s_setprio(1);
#pragma unroll
    for (int c = 0; c < 2; ++c) {
      s16x8 pb = __builtin_bit_cast(s16x8, *(u32x4*)pk[c]);
#pragma unroll
      for (int dsub = 0; dsub < 4; ++dsub) {
        int row = dsub * 16 + r16;
        int ch = (c * 4 + g) ^ (row & 7);
        s16x8 av = *(const s16x8*)(Vc + row * 128 + ch * 16);
        accd[dsub] = mfma16(av, pb, accd[dsub]);
      }
    }
    __builtin_amdgcn_s_setprio(0);

    cur ^= 1;
  }

  int b = bh >> 4, h = bh & (HH - 1);
  int srow = qw0 + r16;
  float inv = 1.0f / lrow;
#pragma unroll
  for (int dsub = 0; dsub < 4; ++dsub) {
    int d0 = dsub * 16 + 4 * g;
    u16x4 o;
#pragma unroll
    for (int rr = 0; rr < 4; ++rr) o[rr] = f2bf(accd[dsub][rr] * inv);
    *(u16x4*)&ctx[(((size_t)b * SS + srow) * HH + h) * DK + d0] = o;
  }
#undef STAGE_KV
}

extern "C" void kernel_launch(void* const* d_in, const int* in_sizes, int n_in,
                              void* d_out, int out_size, void* d_ws, size_t ws_size,
                              hipStream_t stream) {
  const float* q = (const float*)d_in[0];
  const float* k = (const float*)d_in[1];
  const float* v = (const float*)d_in[2];
  // d_in[3] = mask: exact causal tril, implemented in-kernel
  const float* Wq = (const float*)d_in[4];
  const float* bq = (const float*)d_in[5];
  const float* Wk = (const float*)d_in[6];
  const float* bk = (const float*)d_in[7];
  const float* Wv = (const float*)d_in[8];
  const float* bv = (const float*)d_in[9];
  const float* Wo = (const float*)d_in[10];
  const float* bo = (const float*)d_in[11];

  // Workspace layout (56 MB):
  //   [ 0, 8)  qb  -> reused as ctx    [ 8,16) kb    [16,24) vb -> reused as VhT
  //   [24,32) WT[4] (WqT,WkT,WvT,WoT; 2 MB each)
  //   [32,40) Qh   [40,48) Kh   [48,56) Vh
  char* ws = (char*)d_ws;
  const size_t MB = 1ull << 20;
  unsigned short* qb = (unsigned short*)(ws + 0 * MB);
  unsigned short* kb = (unsigned short*)(ws + 8 * MB);
  unsigned short* vb = (unsigned short*)(ws + 16 * MB);
  unsigned short* WTbase = (unsigned short*)(ws + 24 * MB);
  unsigned short* WoT = (unsigned short*)(ws + 30 * MB);
  unsigned short* Qh = (unsigned short*)(ws + 32 * MB);
  unsigned short* Kh = (unsigned short*)(ws + 40 * MB);
  unsigned short* Vh = (unsigned short*)(ws + 48 * MB);
  unsigned short* VhT = (unsigned short*)(ws + 16 * MB);  // reuse vb
  unsigned short* ctx = (unsigned short*)(ws + 0 * MB);   // reuse qb

  const int n4 = BB * SS * DD / 4;

  cvt3_kernel<<<dim3(n4 / 256, 3), 256, 0, stream>>>(q, k, v, qb, kb, vb);

  dim3 tb(32, 8);
  transpose_w4_kernel<<<dim3(32, 32, 4), tb, 0, stream>>>(Wq, Wk, Wv, Wo, WTbase);

  gemm_qkv_kernel<<<dim3(8, 96), 256, 0, stream>>>(qb, kb, vb, WTbase,
                                                   bq, bk, bv, Qh, Kh, Vh);

  transpose_v_kernel<<<dim3(SS / 32, DK / 32, BB * HH), tb, 0, stream>>>(Vh, VhT);

  attn_kernel<<<dim3(SS / 64, BB * HH), 256, 0, stream>>>(Qh, Kh, VhT, ctx);

  gemm_out_kernel<<<dim3(16, 32), 256, 0, stream>>>(ctx, WoT, bo, (float*)d_out);
}

// Round 7
// 132.570 us; speedup vs baseline: 2.2514x; 1.0936x over previous
//
#include <hip/hip_runtime.h>
#include <stdint.h>

// Problem constants
#define BB 2
#define SS 2048
#define DD 1024
#define HH 16
#define DK 64

// 0.125 (1/sqrt(DK)) * log2(e): QK^T scores land in log2 domain -> exp2 softmax
#define QSCALE 0.1803368801111204f
// finite mask sentinel: exp2(NEGS - m) == 0 for any real m, and never wins a max;
// avoids (-inf) - (-inf) = NaN hazards in all-masked lane groups.
#define NEGS -1.0e30f

typedef short s16x8 __attribute__((ext_vector_type(8)));
typedef float f32x4 __attribute__((ext_vector_type(4)));
typedef unsigned short u16x4 __attribute__((ext_vector_type(4)));
typedef unsigned int u32x4 __attribute__((ext_vector_type(4)));

static __device__ __forceinline__ unsigned short f2bf(float f) {
  unsigned int u = __builtin_bit_cast(unsigned int, f);
  u = (u + 0x7fffu + ((u >> 16) & 1u)) >> 16;
  return (unsigned short)u;
}

// v_cvt_pk_bf16_f32: lo -> low 16, hi -> high 16 (RTNE)
static __device__ __forceinline__ unsigned int cvtpk(float lo, float hi) {
  unsigned int r;
  asm("v_cvt_pk_bf16_f32 %0, %1, %2" : "=v"(r) : "v"(lo), "v"(hi));
  return r;
}

static __device__ __forceinline__ f32x4 mfma16(s16x8 a, s16x8 b, f32x4 c) {
  return __builtin_amdgcn_mfma_f32_16x16x32_bf16(a, b, c, 0, 0, 0);
}

static __device__ __forceinline__ void gload_lds16(const void* g, void* l) {
  __builtin_amdgcn_global_load_lds(
      (const __attribute__((address_space(1))) unsigned int*)g,
      (__attribute__((address_space(3))) unsigned int*)l, 16, 0, 0);
}

// ---------------- fp32 -> bf16 convert, all 3 tensors in one launch ----------------
__global__ __launch_bounds__(256) void cvt3_kernel(const float* __restrict__ q,
                                                   const float* __restrict__ k,
                                                   const float* __restrict__ v,
                                                   unsigned short* __restrict__ qb,
                                                   unsigned short* __restrict__ kb,
                                                   unsigned short* __restrict__ vb) {
  int sel = blockIdx.y;
  const float* in = (sel == 0) ? q : ((sel == 1) ? k : v);
  unsigned short* out = (sel == 0) ? qb : ((sel == 1) ? kb : vb);
  int i = blockIdx.x * 256 + threadIdx.x;
  f32x4 vv = ((const f32x4*)in)[i];
  u16x4 o;
  o.x = f2bf(vv.x); o.y = f2bf(vv.y); o.z = f2bf(vv.z); o.w = f2bf(vv.w);
  ((u16x4*)out)[i] = o;
}

// ---------------- all 4 W [K][N] fp32 -> WT [N][K] bf16 in one launch ----------------
__global__ __launch_bounds__(256) void transpose_w4_kernel(const float* __restrict__ Wq,
                                                           const float* __restrict__ Wk,
                                                           const float* __restrict__ Wv,
                                                           const float* __restrict__ Wo,
                                                           unsigned short* __restrict__ WTbase) {
  __shared__ float t[32][33];
  int z = blockIdx.z;
  const float* W = (z == 0) ? Wq : ((z == 1) ? Wk : ((z == 2) ? Wv : Wo));
  float scale = (z == 0) ? QSCALE : 1.0f;
  unsigned short* WT = WTbase + (size_t)z * DD * DD;
  int n0 = blockIdx.x * 32, k0 = blockIdx.y * 32;
  int tx = threadIdx.x, ty = threadIdx.y;
  for (int i = 0; i < 4; ++i)
    t[ty + 8 * i][tx] = W[(size_t)(k0 + ty + 8 * i) * DD + n0 + tx];
  __syncthreads();
  for (int i = 0; i < 4; ++i)
    WT[(size_t)(n0 + ty + 8 * i) * DD + k0 + tx] = f2bf(t[tx][ty + 8 * i] * scale);
}

// ---------------- V [bh][S][DK] bf16 -> VT [bh][DK][S] bf16 ----------------
__global__ __launch_bounds__(256) void transpose_v_kernel(const unsigned short* __restrict__ V,
                                                          unsigned short* __restrict__ VT) {
  __shared__ unsigned short t[32][33];
  int s0 = blockIdx.x * 32, d0 = blockIdx.y * 32, bh = blockIdx.z;
  int tx = threadIdx.x, ty = threadIdx.y;
  const unsigned short* Vb = V + (size_t)bh * SS * DK;
  unsigned short* Tb = VT + (size_t)bh * DK * SS;
  for (int i = 0; i < 4; ++i)
    t[ty + 8 * i][tx] = Vb[(size_t)(s0 + ty + 8 * i) * DK + d0 + tx];
  __syncthreads();
  for (int i = 0; i < 4; ++i)
    Tb[(size_t)(d0 + ty + 8 * i) * SS + s0 + tx] = t[tx][ty + 8 * i];
}

// ---------------- fused QKV projection GEMM ----------------
// grid (8, 96): blockIdx.y>>5 selects {Q,K,V}; (blockIdx.y&31)*128 = m0
__global__ __launch_bounds__(256) void gemm_qkv_kernel(
    const unsigned short* __restrict__ qb, const unsigned short* __restrict__ kb,
    const unsigned short* __restrict__ vb, const unsigned short* __restrict__ WTbase,
    const float* __restrict__ bq, const float* __restrict__ bk,
    const float* __restrict__ bv, unsigned short* __restrict__ Qh,
    unsigned short* __restrict__ Kh, unsigned short* __restrict__ Vh) {
  const int K = DD;
  __shared__ __align__(16) unsigned short Alds[128 * 32];
  __shared__ __align__(16) unsigned short Blds[128 * 32];
  int tid = threadIdx.x;
  int lane = tid & 63, wave = tid >> 6;
  int g = lane >> 4, r16 = lane & 15;
  int seg = blockIdx.y >> 5;
  int m0 = (blockIdx.y & 31) * 128, n0 = blockIdx.x * 128;
  int wm = (wave >> 1) * 64, wn = (wave & 1) * 64;

  const unsigned short* A = (seg == 0) ? qb : ((seg == 1) ? kb : vb);
  const unsigned short* BT = WTbase + (size_t)seg * DD * DD;
  const float* bias = (seg == 0) ? bq : ((seg == 1) ? bk : bv);
  unsigned short* outh = (seg == 0) ? Qh : ((seg == 1) ? Kh : Vh);
  float bsc = (seg == 0) ? QSCALE : 1.0f;

  f32x4 acc[4][4] = {};

  int c0 = tid, c1 = tid + 256;
  int arow0 = c0 >> 2, arow1 = c1 >> 2;
  int as0 = (c0 & 3) ^ ((arow0 >> 1) & 3);
  int as1 = (c1 & 3) ^ ((arow1 >> 1) & 3);

  for (int k0 = 0; k0 < K; k0 += 32) {
    __syncthreads();
    gload_lds16((const char*)(A + (size_t)(m0 + arow0) * K + k0) + as0 * 16,
                (char*)Alds + wave * 1024);
    gload_lds16((const char*)(A + (size_t)(m0 + arow1) * K + k0) + as1 * 16,
                (char*)Alds + wave * 1024 + 4096);
    gload_lds16((const char*)(BT + (size_t)(n0 + arow0) * K + k0) + as0 * 16,
                (char*)Blds + wave * 1024);
    gload_lds16((const char*)(BT + (size_t)(n0 + arow1) * K + k0) + as1 * 16,
                (char*)Blds + wave * 1024 + 4096);
    __syncthreads();

    s16x8 af[4], bfr[4];
#pragma unroll
    for (int mt = 0; mt < 4; ++mt) {
      int row = wm + mt * 16 + r16;
      int ch = g ^ ((row >> 1) & 3);
      af[mt] = *(const s16x8*)((const char*)Alds + row * 64 + ch * 16);
    }
#pragma unroll
    for (int nt = 0; nt < 4; ++nt) {
      int row = wn + nt * 16 + r16;
      int ch = g ^ ((row >> 1) & 3);
      bfr[nt] = *(const s16x8*)((const char*)Blds + row * 64 + ch * 16);
    }
#pragma unroll
    for (int mt = 0; mt < 4; ++mt)
#pragma unroll
      for (int nt = 0; nt < 4; ++nt)
        acc[mt][nt] = mfma16(af[mt], bfr[nt], acc[mt][nt]);
  }

#pragma unroll
  for (int nt = 0; nt < 4; ++nt) {
    int col = n0 + wn + nt * 16 + r16;
    int h = col >> 6, dk = col & (DK - 1);
    float bvv = bias[col] * bsc;
#pragma unroll
    for (int mt = 0; mt < 4; ++mt) {
#pragma unroll
      for (int rr = 0; rr < 4; ++rr) {
        int rowg = m0 + wm + mt * 16 + g * 4 + rr;
        int bb = rowg >> 11, s = rowg & (SS - 1);
        float val = acc[mt][nt][rr] + bvv;
        outh[(((size_t)bb * HH + h) * SS + s) * DK + dk] = f2bf(val);
      }
    }
  }
}

// ---------------- output GEMM: C[4096][1024] = ctx @ WoT^T + bo (fp32), 128x64 tile ----------------
__global__ __launch_bounds__(256) void gemm_out_kernel(const unsigned short* __restrict__ A,
                                                       const unsigned short* __restrict__ BT,
                                                       const float* __restrict__ bias,
                                                       float* __restrict__ out) {
  const int K = DD;
  __shared__ __align__(16) unsigned short Alds[128 * 32];
  __shared__ __align__(16) unsigned short Blds[64 * 32];
  int tid = threadIdx.x;
  int lane = tid & 63, wave = tid >> 6;
  int g = lane >> 4, r16 = lane & 15;
  int m0 = blockIdx.y * 128, n0 = blockIdx.x * 64;
  int wm = (wave >> 1) * 64, wn = (wave & 1) * 32;

  f32x4 acc[4][2] = {};

  int c0 = tid, c1 = tid + 256;
  int arow0 = c0 >> 2, arow1 = c1 >> 2;
  int as0 = (c0 & 3) ^ ((arow0 >> 1) & 3);
  int as1 = (c1 & 3) ^ ((arow1 >> 1) & 3);

  for (int k0 = 0; k0 < K; k0 += 32) {
    __syncthreads();
    gload_lds16((const char*)(A + (size_t)(m0 + arow0) * K + k0) + as0 * 16,
                (char*)Alds + wave * 1024);
    gload_lds16((const char*)(A + (size_t)(m0 + arow1) * K + k0) + as1 * 16,
                (char*)Alds + wave * 1024 + 4096);
    gload_lds16((const char*)(BT + (size_t)(n0 + arow0) * K + k0) + as0 * 16,
                (char*)Blds + wave * 1024);
    __syncthreads();

    s16x8 af[4], bfr[2];
#pragma unroll
    for (int mt = 0; mt < 4; ++mt) {
      int row = wm + mt * 16 + r16;
      int ch = g ^ ((row >> 1) & 3);
      af[mt] = *(const s16x8*)((const char*)Alds + row * 64 + ch * 16);
    }
#pragma unroll
    for (int nt = 0; nt < 2; ++nt) {
      int row = wn + nt * 16 + r16;
      int ch = g ^ ((row >> 1) & 3);
      bfr[nt] = *(const s16x8*)((const char*)Blds + row * 64 + ch * 16);
    }
#pragma unroll
    for (int mt = 0; mt < 4; ++mt)
#pragma unroll
      for (int nt = 0; nt < 2; ++nt)
        acc[mt][nt] = mfma16(af[mt], bfr[nt], acc[mt][nt]);
  }

#pragma unroll
  for (int nt = 0; nt < 2; ++nt) {
    int col = n0 + wn + nt * 16 + r16;
    float bvv = bias[col];
#pragma unroll
    for (int mt = 0; mt < 4; ++mt) {
#pragma unroll
      for (int rr = 0; rr < 4; ++rr) {
        int rowg = m0 + wm + mt * 16 + g * 4 + rr;
        out[(size_t)rowg * DD + col] = acc[mt][nt][rr] + bvv;
      }
    }
  }
}

// ---------------- causal flash attention, paired q-tiles, in-register softmax ----------------
// Each block processes q-tile pid and q-tile (31-pid): (pid+1) + (32-pid) = 33 kv-tiles
// uniform per block -> grid 512 blocks, exactly 2 resident blocks/CU, no tail.
// Swapped QK^T: S^T = mfma(A=K-rows(permuted), B=Q) -> lane col = q.
// Key perm: subtile nt covers key = 8g + 4*(nt&1) + rr + 32*(nt>>1) so each lane
// holds keys 8g..8g+7 of each 32-chunk -> PV B-operand (P^T) is lane-local.
// Scores arrive in log2 domain (log2e folded into Wq): softmax uses exp2.
__global__ __launch_bounds__(256) void attn_kernel(const unsigned short* __restrict__ Qh,
                                                   const unsigned short* __restrict__ Kh,
                                                   const unsigned short* __restrict__ VhT,
                                                   unsigned short* __restrict__ ctx) {
  __shared__ __align__(16) unsigned short Klds[2][64 * 64];  // [key][dk], swz (r&3)|(((r>>3)&1)<<2)
  __shared__ __align__(16) unsigned short Vlds[2][64 * 64];  // [d][key], swz r&7

  int tid = threadIdx.x;
  int lane = tid & 63, wave = tid >> 6;
  int g = lane >> 4, r16 = lane & 15;
  int pid = blockIdx.x;  // 0..15
  int bh = blockIdx.y;

  const int NTQ = SS / 64;  // 32 q-tiles per head
  int q0A = pid * 64, q0B = (NTQ - 1 - pid) * 64;
  int tilesA = pid + 1, tilesB = NTQ - pid;

  const unsigned short* Qb = Qh + (size_t)bh * SS * DK;
  const char* Kb = (const char*)(Kh + (size_t)bh * SS * DK);
  const char* Vb = (const char*)(VhT + (size_t)bh * DK * SS);

  // K-frag read constants: row(nt) = 8a + b + 4*(nt&1) + 32*(nt>>1); swizzle sk = b + 4*(a&1)
  int a_ = r16 >> 2, b_ = r16 & 3;
  int rbase = 8 * a_ + b_;
  int sk = b_ + 4 * (a_ & 1);

  // staging: 1024 chunks of 16B (K 512 + V 512); chunk c -> row=c>>3, col=c&7; pre-swz src
  int c0 = tid, c1 = tid + 256;
  int row0 = c0 >> 3, row1 = c1 >> 3;
  int skst0 = ((row0 & 3) | (((row0 >> 3) & 1) << 2));
  int skst1 = ((row1 & 3) | (((row1 >> 3) & 1) << 2));
  int kc0 = (c0 & 7) ^ skst0, kc1 = (c1 & 7) ^ skst1;
  int vc0 = (c0 & 7) ^ (row0 & 7), vc1 = (c1 & 7) ^ (row1 & 7);

#define STAGE_KV(buf, kv0)                                                   \
  do {                                                                       \
    gload_lds16(Kb + ((size_t)((kv0) + row0) * 128) + kc0 * 16,              \
                (char*)Klds[buf] + wave * 1024);                             \
    gload_lds16(Kb + ((size_t)((kv0) + row1) * 128) + kc1 * 16,              \
                (char*)Klds[buf] + wave * 1024 + 4096);                      \
    gload_lds16(Vb + ((size_t)row0 * SS + (kv0)) * 2 + vc0 * 16,             \
                (char*)Vlds[buf] + wave * 1024);                             \
    gload_lds16(Vb + ((size_t)row1 * SS + (kv0)) * 2 + vc1 * 16,             \
                (char*)Vlds[buf] + wave * 1024 + 4096);                      \
  } while (0)

  int b = bh >> 4, h = bh & (HH - 1);

  STAGE_KV(0, 0);
  int cur = 0;

  for (int seg = 0; seg < 2; ++seg) {
    int q0 = seg ? q0B : q0A;
    int ntiles = seg ? tilesB : tilesA;
    int qw0 = q0 + wave * 16;

    // Q as B-operand: lane holds Q[qw0+r16][kc*32+8g..+7]
    s16x8 aq[2];
#pragma unroll
    for (int kc = 0; kc < 2; ++kc)
      aq[kc] = *(const s16x8*)(Qb + (size_t)(qw0 + r16) * DK + kc * 32 + g * 8);

    f32x4 accd[4] = {};  // [dsub]: O^T[d=dsub*16+4g+rr][q=qw0+r16]
    float mrow = -INFINITY, lrow = 0.0f;

    for (int t = 0; t < ntiles; ++t) {
      int kv0 = t * 64;
      __syncthreads();  // implicit vmcnt(0): buf[cur] staged, buf[cur^1] consumed
      bool more = (t + 1 < ntiles);
      if (more || seg == 0) STAGE_KV(cur ^ 1, more ? kv0 + 64 : 0);

      const char* Kc = (const char*)Klds[cur];
      const char* Vc = (const char*)Vlds[cur];

      // ---- QK^T (swapped): sf[nt][rr] = S[key = kv0+8g+4(nt&1)+rr+32(nt>>1)][q = qw0+r16]
      f32x4 sf[4] = {};
      __builtin_amdgcn_s_setprio(1);
#pragma unroll
      for (int kc = 0; kc < 2; ++kc) {
        s16x8 bk[4];
#pragma unroll
        for (int nt = 0; nt < 4; ++nt) {
          int row = rbase + 4 * (nt & 1) + 32 * (nt >> 1);
          int ch = (kc * 4 + g) ^ sk;
          bk[nt] = *(const s16x8*)(Kc + row * 128 + ch * 16);
        }
#pragma unroll
        for (int nt = 0; nt < 4; ++nt)
          sf[nt] = mfma16(bk[nt], aq[kc], sf[nt]);
      }
      __builtin_amdgcn_s_setprio(0);

      // ---- prefetch V fragments (hides LDS latency under softmax VALU)
      s16x8 av[2][4];
#pragma unroll
      for (int c = 0; c < 2; ++c)
#pragma unroll
        for (int dsub = 0; dsub < 4; ++dsub) {
          int row = dsub * 16 + r16;
          int ch = (c * 4 + g) ^ (row & 7);
          av[c][dsub] = *(const s16x8*)(Vc + row * 128 + ch * 16);
        }

      // ---- mask (diagonal tiles only; wave-uniform branch); finite sentinel
      if (kv0 + 63 > qw0) {
        int thr = qw0 + r16 - kv0 - 8 * g;  // key offset limit
#pragma unroll
        for (int nt = 0; nt < 4; ++nt) {
          int koff = 4 * (nt & 1) + 32 * (nt >> 1);
#pragma unroll
          for (int rr = 0; rr < 4; ++rr)
            if (koff + rr > thr) sf[nt][rr] = NEGS;
        }
      }

      // ---- online softmax (log2 domain); shfl_xor 16/32 (proven r5 path)
      float tmax = NEGS;
#pragma unroll
      for (int nt = 0; nt < 4; ++nt)
#pragma unroll
        for (int rr = 0; rr < 4; ++rr) tmax = fmaxf(tmax, sf[nt][rr]);
      tmax = fmaxf(tmax, __shfl_xor(tmax, 16));
      tmax = fmaxf(tmax, __shfl_xor(tmax, 32));

      if (!__all(tmax <= mrow)) {  // exact defer: skip is numerically identical
        float mn = fmaxf(mrow, tmax);
        float fc = __builtin_amdgcn_exp2f(mrow - mn);
        lrow *= fc;
        mrow = mn;
#pragma unroll
        for (int dsub = 0; dsub < 4; ++dsub)
#pragma unroll
          for (int rr = 0; rr < 4; ++rr) accd[dsub][rr] *= fc;
      }

      float pf[4][4];
      float su = 0.0f;
#pragma unroll
      for (int nt = 0; nt < 4; ++nt)
#pragma unroll
        for (int rr = 0; rr < 4; ++rr) {
          float p = __builtin_amdgcn_exp2f(sf[nt][rr] - mrow);
          pf[nt][rr] = p;
          su += p;
        }
      su += __shfl_xor(su, 16);
      su += __shfl_xor(su, 32);
      lrow += su;

      // pack P^T fragments: chunk c holds keys c*32 + 8g..+7 in k-ascending order
      unsigned int pk[2][4];
#pragma unroll
      for (int c = 0; c < 2; ++c) {
        pk[c][0] = cvtpk(pf[2 * c][0], pf[2 * c][1]);
        pk[c][1] = cvtpk(pf[2 * c][2], pf[2 * c][3]);
        pk[c][2] = cvtpk(pf[2 * c + 1][0], pf[2 * c + 1][1]);
        pk[c][3] = cvtpk(pf[2 * c + 1][2], pf[2 * c + 1][3]);
      }

      // ---- PV (swapped): accd[dsub] += mfma(A=V^T rows, B=P^T)
      __builtin_amdgcn_s_setprio(1);
#pragma unroll
      for (int c = 0; c < 2; ++c) {
        s16x8 pb = __builtin_bit_cast(s16x8, *(u32x4*)pk[c]);
#pragma unroll
        for (int dsub = 0; dsub < 4; ++dsub)
          accd[dsub] = mfma16(av[c][dsub], pb, accd[dsub]);
      }
      __builtin_amdgcn_s_setprio(0);

      cur ^= 1;
    }

    int srow = qw0 + r16;
    float inv = 1.0f / lrow;
#pragma unroll
    for (int dsub = 0; dsub < 4; ++dsub) {
      int d0 = dsub * 16 + 4 * g;
      u16x4 o;
#pragma unroll
      for (int rr = 0; rr < 4; ++rr) o[rr] = f2bf(accd[dsub][rr] * inv);
      *(u16x4*)&ctx[(((size_t)b * SS + srow) * HH + h) * DK + d0] = o;
    }
  }
#undef STAGE_KV
}

extern "C" void kernel_launch(void* const* d_in, const int* in_sizes, int n_in,
                              void* d_out, int out_size, void* d_ws, size_t ws_size,
                              hipStream_t stream) {
  const float* q = (const float*)d_in[0];
  const float* k = (const float*)d_in[1];
  const float* v = (const float*)d_in[2];
  // d_in[3] = mask: exact causal tril, implemented in-kernel
  const float* Wq = (const float*)d_in[4];
  const float* bq = (const float*)d_in[5];
  const float* Wk = (const float*)d_in[6];
  const float* bk = (const float*)d_in[7];
  const float* Wv = (const float*)d_in[8];
  const float* bv = (const float*)d_in[9];
  const float* Wo = (const float*)d_in[10];
  const float* bo = (const float*)d_in[11];

  // Workspace layout (56 MB):
  //   [ 0, 8)  qb  -> reused as ctx    [ 8,16) kb    [16,24) vb -> reused as VhT
  //   [24,32) WT[4] (WqT,WkT,WvT,WoT; 2 MB each)
  //   [32,40) Qh   [40,48) Kh   [48,56) Vh
  char* ws = (char*)d_ws;
  const size_t MB = 1ull << 20;
  unsigned short* qb = (unsigned short*)(ws + 0 * MB);
  unsigned short* kb = (unsigned short*)(ws + 8 * MB);
  unsigned short* vb = (unsigned short*)(ws + 16 * MB);
  unsigned short* WTbase = (unsigned short*)(ws + 24 * MB);
  unsigned short* WoT = (unsigned short*)(ws + 30 * MB);
  unsigned short* Qh = (unsigned short*)(ws + 32 * MB);
  unsigned short* Kh = (unsigned short*)(ws + 40 * MB);
  unsigned short* Vh = (unsigned short*)(ws + 48 * MB);
  unsigned short* VhT = (unsigned short*)(ws + 16 * MB);  // reuse vb
  unsigned short* ctx = (unsigned short*)(ws + 0 * MB);   // reuse qb

  const int n4 = BB * SS * DD / 4;

  cvt3_kernel<<<dim3(n4 / 256, 3), 256, 0, stream>>>(q, k, v, qb, kb, vb);

  dim3 tb(32, 8);
  transpose_w4_kernel<<<dim3(32, 32, 4), tb, 0, stream>>>(Wq, Wk, Wv, Wo, WTbase);

  gemm_qkv_kernel<<<dim3(8, 96), 256, 0, stream>>>(qb, kb, vb, WTbase,
                                                   bq, bk, bv, Qh, Kh, Vh);

  transpose_v_kernel<<<dim3(SS / 32, DK / 32, BB * HH), tb, 0, stream>>>(Vh, VhT);

  attn_kernel<<<dim3(SS / 128, BB * HH), 256, 0, stream>>>(Qh, Kh, VhT, ctx);

  gemm_out_kernel<<<dim3(16, 32), 256, 0, stream>>>(ctx, WoT, bo, (float*)d_out);
}

// Round 8
// 130.372 us; speedup vs baseline: 2.2893x; 1.0169x over previous
//
#include <hip/hip_runtime.h>
#include <stdint.h>

// Problem constants
#define BB 2
#define SS 2048
#define DD 1024
#define HH 16
#define DK 64

// 0.125 (1/sqrt(DK)) * log2(e): QK^T scores land in log2 domain -> exp2 softmax
#define QSCALE 0.1803368801111204f
// finite mask sentinel: exp2(NEGS - m) == 0 for any real m, and never wins a max;
// avoids (-inf) - (-inf) = NaN hazards in all-masked lane groups.
#define NEGS -1.0e30f

typedef short s16x8 __attribute__((ext_vector_type(8)));
typedef float f32x4 __attribute__((ext_vector_type(4)));
typedef unsigned short u16x4 __attribute__((ext_vector_type(4)));
typedef unsigned int u32x4 __attribute__((ext_vector_type(4)));

static __device__ __forceinline__ unsigned short f2bf(float f) {
  unsigned int u = __builtin_bit_cast(unsigned int, f);
  u = (u + 0x7fffu + ((u >> 16) & 1u)) >> 16;
  return (unsigned short)u;
}

// v_cvt_pk_bf16_f32: lo -> low 16, hi -> high 16 (RTNE)
static __device__ __forceinline__ unsigned int cvtpk(float lo, float hi) {
  unsigned int r;
  asm("v_cvt_pk_bf16_f32 %0, %1, %2" : "=v"(r) : "v"(lo), "v"(hi));
  return r;
}

static __device__ __forceinline__ f32x4 mfma16(s16x8 a, s16x8 b, f32x4 c) {
  return __builtin_amdgcn_mfma_f32_16x16x32_bf16(a, b, c, 0, 0, 0);
}

static __device__ __forceinline__ void gload_lds16(const void* g, void* l) {
  __builtin_amdgcn_global_load_lds(
      (const __attribute__((address_space(1))) unsigned int*)g,
      (__attribute__((address_space(3))) unsigned int*)l, 16, 0, 0);
}

// ---------------- fp32 -> bf16 convert, all 3 tensors in one launch ----------------
__global__ __launch_bounds__(256) void cvt3_kernel(const float* __restrict__ q,
                                                   const float* __restrict__ k,
                                                   const float* __restrict__ v,
                                                   unsigned short* __restrict__ qb,
                                                   unsigned short* __restrict__ kb,
                                                   unsigned short* __restrict__ vb) {
  int sel = blockIdx.y;
  const float* in = (sel == 0) ? q : ((sel == 1) ? k : v);
  unsigned short* out = (sel == 0) ? qb : ((sel == 1) ? kb : vb);
  int i = blockIdx.x * 256 + threadIdx.x;
  f32x4 vv = ((const f32x4*)in)[i];
  u16x4 o;
  o.x = f2bf(vv.x); o.y = f2bf(vv.y); o.z = f2bf(vv.z); o.w = f2bf(vv.w);
  ((u16x4*)out)[i] = o;
}

// ---------------- all 4 W [K][N] fp32 -> WT [N][K] bf16 in one launch ----------------
__global__ __launch_bounds__(256) void transpose_w4_kernel(const float* __restrict__ Wq,
                                                           const float* __restrict__ Wk,
                                                           const float* __restrict__ Wv,
                                                           const float* __restrict__ Wo,
                                                           unsigned short* __restrict__ WTbase) {
  __shared__ float t[32][33];
  int z = blockIdx.z;
  const float* W = (z == 0) ? Wq : ((z == 1) ? Wk : ((z == 2) ? Wv : Wo));
  float scale = (z == 0) ? QSCALE : 1.0f;
  unsigned short* WT = WTbase + (size_t)z * DD * DD;
  int n0 = blockIdx.x * 32, k0 = blockIdx.y * 32;
  int tx = threadIdx.x, ty = threadIdx.y;
  for (int i = 0; i < 4; ++i)
    t[ty + 8 * i][tx] = W[(size_t)(k0 + ty + 8 * i) * DD + n0 + tx];
  __syncthreads();
  for (int i = 0; i < 4; ++i)
    WT[(size_t)(n0 + ty + 8 * i) * DD + k0 + tx] = f2bf(t[tx][ty + 8 * i] * scale);
}

// ---------------- V [bh][S][DK] bf16 -> VT [bh][DK][S] bf16 ----------------
__global__ __launch_bounds__(256) void transpose_v_kernel(const unsigned short* __restrict__ V,
                                                          unsigned short* __restrict__ VT) {
  __shared__ unsigned short t[32][33];
  int s0 = blockIdx.x * 32, d0 = blockIdx.y * 32, bh = blockIdx.z;
  int tx = threadIdx.x, ty = threadIdx.y;
  const unsigned short* Vb = V + (size_t)bh * SS * DK;
  unsigned short* Tb = VT + (size_t)bh * DK * SS;
  for (int i = 0; i < 4; ++i)
    t[ty + 8 * i][tx] = Vb[(size_t)(s0 + ty + 8 * i) * DK + d0 + tx];
  __syncthreads();
  for (int i = 0; i < 4; ++i)
    Tb[(size_t)(d0 + ty + 8 * i) * SS + s0 + tx] = t[tx][ty + 8 * i];
}

// ---------------- fused QKV projection GEMM ----------------
// grid (8, 96): blockIdx.y>>5 selects {Q,K,V}; (blockIdx.y&31)*128 = m0
__global__ __launch_bounds__(256) void gemm_qkv_kernel(
    const unsigned short* __restrict__ qb, const unsigned short* __restrict__ kb,
    const unsigned short* __restrict__ vb, const unsigned short* __restrict__ WTbase,
    const float* __restrict__ bq, const float* __restrict__ bk,
    const float* __restrict__ bv, unsigned short* __restrict__ Qh,
    unsigned short* __restrict__ Kh, unsigned short* __restrict__ Vh) {
  const int K = DD;
  __shared__ __align__(16) unsigned short Alds[128 * 32];
  __shared__ __align__(16) unsigned short Blds[128 * 32];
  int tid = threadIdx.x;
  int lane = tid & 63, wave = tid >> 6;
  int g = lane >> 4, r16 = lane & 15;
  int seg = blockIdx.y >> 5;
  int m0 = (blockIdx.y & 31) * 128, n0 = blockIdx.x * 128;
  int wm = (wave >> 1) * 64, wn = (wave & 1) * 64;

  const unsigned short* A = (seg == 0) ? qb : ((seg == 1) ? kb : vb);
  const unsigned short* BT = WTbase + (size_t)seg * DD * DD;
  const float* bias = (seg == 0) ? bq : ((seg == 1) ? bk : bv);
  unsigned short* outh = (seg == 0) ? Qh : ((seg == 1) ? Kh : Vh);
  float bsc = (seg == 0) ? QSCALE : 1.0f;

  f32x4 acc[4][4] = {};

  int c0 = tid, c1 = tid + 256;
  int arow0 = c0 >> 2, arow1 = c1 >> 2;
  int as0 = (c0 & 3) ^ ((arow0 >> 1) & 3);
  int as1 = (c1 & 3) ^ ((arow1 >> 1) & 3);

  for (int k0 = 0; k0 < K; k0 += 32) {
    __syncthreads();
    gload_lds16((const char*)(A + (size_t)(m0 + arow0) * K + k0) + as0 * 16,
                (char*)Alds + wave * 1024);
    gload_lds16((const char*)(A + (size_t)(m0 + arow1) * K + k0) + as1 * 16,
                (char*)Alds + wave * 1024 + 4096);
    gload_lds16((const char*)(BT + (size_t)(n0 + arow0) * K + k0) + as0 * 16,
                (char*)Blds + wave * 1024);
    gload_lds16((const char*)(BT + (size_t)(n0 + arow1) * K + k0) + as1 * 16,
                (char*)Blds + wave * 1024 + 4096);
    __syncthreads();

    s16x8 af[4], bfr[4];
#pragma unroll
    for (int mt = 0; mt < 4; ++mt) {
      int row = wm + mt * 16 + r16;
      int ch = g ^ ((row >> 1) & 3);
      af[mt] = *(const s16x8*)((const char*)Alds + row * 64 + ch * 16);
    }
#pragma unroll
    for (int nt = 0; nt < 4; ++nt) {
      int row = wn + nt * 16 + r16;
      int ch = g ^ ((row >> 1) & 3);
      bfr[nt] = *(const s16x8*)((const char*)Blds + row * 64 + ch * 16);
    }
#pragma unroll
    for (int mt = 0; mt < 4; ++mt)
#pragma unroll
      for (int nt = 0; nt < 4; ++nt)
        acc[mt][nt] = mfma16(af[mt], bfr[nt], acc[mt][nt]);
  }

#pragma unroll
  for (int nt = 0; nt < 4; ++nt) {
    int col = n0 + wn + nt * 16 + r16;
    int h = col >> 6, dk = col & (DK - 1);
    float bvv = bias[col] * bsc;
#pragma unroll
    for (int mt = 0; mt < 4; ++mt) {
#pragma unroll
      for (int rr = 0; rr < 4; ++rr) {
        int rowg = m0 + wm + mt * 16 + g * 4 + rr;
        int bb = rowg >> 11, s = rowg & (SS - 1);
        float val = acc[mt][nt][rr] + bvv;
        outh[(((size_t)bb * HH + h) * SS + s) * DK + dk] = f2bf(val);
      }
    }
  }
}

// ---------------- output GEMM: C[4096][1024] = ctx @ WoT^T + bo (fp32), 128x64 tile ----------------
__global__ __launch_bounds__(256) void gemm_out_kernel(const unsigned short* __restrict__ A,
                                                       const unsigned short* __restrict__ BT,
                                                       const float* __restrict__ bias,
                                                       float* __restrict__ out) {
  const int K = DD;
  __shared__ __align__(16) unsigned short Alds[128 * 32];
  __shared__ __align__(16) unsigned short Blds[64 * 32];
  int tid = threadIdx.x;
  int lane = tid & 63, wave = tid >> 6;
  int g = lane >> 4, r16 = lane & 15;
  int m0 = blockIdx.y * 128, n0 = blockIdx.x * 64;
  int wm = (wave >> 1) * 64, wn = (wave & 1) * 32;

  f32x4 acc[4][2] = {};

  int c0 = tid, c1 = tid + 256;
  int arow0 = c0 >> 2, arow1 = c1 >> 2;
  int as0 = (c0 & 3) ^ ((arow0 >> 1) & 3);
  int as1 = (c1 & 3) ^ ((arow1 >> 1) & 3);

  for (int k0 = 0; k0 < K; k0 += 32) {
    __syncthreads();
    gload_lds16((const char*)(A + (size_t)(m0 + arow0) * K + k0) + as0 * 16,
                (char*)Alds + wave * 1024);
    gload_lds16((const char*)(A + (size_t)(m0 + arow1) * K + k0) + as1 * 16,
                (char*)Alds + wave * 1024 + 4096);
    gload_lds16((const char*)(BT + (size_t)(n0 + arow0) * K + k0) + as0 * 16,
                (char*)Blds + wave * 1024);
    __syncthreads();

    s16x8 af[4], bfr[2];
#pragma unroll
    for (int mt = 0; mt < 4; ++mt) {
      int row = wm + mt * 16 + r16;
      int ch = g ^ ((row >> 1) & 3);
      af[mt] = *(const s16x8*)((const char*)Alds + row * 64 + ch * 16);
    }
#pragma unroll
    for (int nt = 0; nt < 2; ++nt) {
      int row = wn + nt * 16 + r16;
      int ch = g ^ ((row >> 1) & 3);
      bfr[nt] = *(const s16x8*)((const char*)Blds + row * 64 + ch * 16);
    }
#pragma unroll
    for (int mt = 0; mt < 4; ++mt)
#pragma unroll
      for (int nt = 0; nt < 2; ++nt)
        acc[mt][nt] = mfma16(af[mt], bfr[nt], acc[mt][nt]);
  }

#pragma unroll
  for (int nt = 0; nt < 2; ++nt) {
    int col = n0 + wn + nt * 16 + r16;
    float bvv = bias[col];
#pragma unroll
    for (int mt = 0; mt < 4; ++mt) {
#pragma unroll
      for (int rr = 0; rr < 4; ++rr) {
        int rowg = m0 + wm + mt * 16 + g * 4 + rr;
        out[(size_t)rowg * DD + col] = acc[mt][nt][rr] + bvv;
      }
    }
  }
}

// ---------------- causal flash attention ----------------
// Paired q-tiles (pid, 31-pid): 33 kv-tiles/block uniform; 512 blocks.
// XCD-aware bid: bid = (bh&7) + 8*(pid + 16*(bh>>3)) -> all blocks of a head on
// one XCD (bid%8 round-robin), 4 heads/XCD ~= 3MB KV+Q working set < 4MB L2.
// Triple-buffered staging with counted vmcnt: stage(t+2) issued after barrier;
// s_waitcnt vmcnt(4) (not 0) before each barrier keeps 4-8 loads in flight.
// Per-wave vmcnt(4) => that wave's stage(t) chunk landed; barrier publishes.
// Swapped QK^T/PV + in-register softmax as in r7 (proven).
__global__ __launch_bounds__(256) void attn_kernel(const unsigned short* __restrict__ Qh,
                                                   const unsigned short* __restrict__ Kh,
                                                   const unsigned short* __restrict__ VhT,
                                                   unsigned short* __restrict__ ctx) {
  __shared__ __align__(16) unsigned short Klds[3][64 * 64];  // [key][dk], swz (r&3)|(((r>>3)&1)<<2)
  __shared__ __align__(16) unsigned short Vlds[3][64 * 64];  // [d][key], swz r&7

  int tid = threadIdx.x;
  int lane = tid & 63, wave = tid >> 6;
  int g = lane >> 4, r16 = lane & 15;
  int bid = blockIdx.x;
  int bh = ((bid >> 7) << 3) | (bid & 7);
  int pid = (bid >> 3) & 15;

  const int NTQ = SS / 64;  // 32 q-tiles per head
  int q0A = pid * 64, q0B = (NTQ - 1 - pid) * 64;
  int tilesA = pid + 1;
  int NT = NTQ + 1;  // tilesA + tilesB = 33

  const unsigned short* Qb = Qh + (size_t)bh * SS * DK;
  const char* Kb = (const char*)(Kh + (size_t)bh * SS * DK);
  const char* Vb = (const char*)(VhT + (size_t)bh * DK * SS);

  // K-frag read constants: row(nt) = 8a + b + 4*(nt&1) + 32*(nt>>1); swizzle sk = b + 4*(a&1)
  int a_ = r16 >> 2, b_ = r16 & 3;
  int rbase = 8 * a_ + b_;
  int sk = b_ + 4 * (a_ & 1);

  // staging: per tile 8 chunks of 16B per thread-pair group; pre-swizzled source
  int c0 = tid, c1 = tid + 256;
  int row0 = c0 >> 3, row1 = c1 >> 3;
  int skst0 = ((row0 & 3) | (((row0 >> 3) & 1) << 2));
  int skst1 = ((row1 & 3) | (((row1 >> 3) & 1) << 2));
  int kc0 = (c0 & 7) ^ skst0, kc1 = (c1 & 7) ^ skst1;
  int vc0 = (c0 & 7) ^ (row0 & 7), vc1 = (c1 & 7) ^ (row1 & 7);

#define KV_OF(t) ((((t) >= tilesA) ? (t) - tilesA : (t)) * 64)
#define STAGE_KV(buf, kv0)                                                   \
  do {                                                                       \
    gload_lds16(Kb + ((size_t)((kv0) + row0) * 128) + kc0 * 16,              \
                (char*)Klds[buf] + wave * 1024);                             \
    gload_lds16(Kb + ((size_t)((kv0) + row1) * 128) + kc1 * 16,              \
                (char*)Klds[buf] + wave * 1024 + 4096);                      \
    gload_lds16(Vb + ((size_t)row0 * SS + (kv0)) * 2 + vc0 * 16,             \
                (char*)Vlds[buf] + wave * 1024);                             \
    gload_lds16(Vb + ((size_t)row1 * SS + (kv0)) * 2 + vc1 * 16,             \
                (char*)Vlds[buf] + wave * 1024 + 4096);                      \
  } while (0)

  int b = bh >> 4, h = bh & (HH - 1);

  // segment A state
  int qw0 = q0A + wave * 16;
  s16x8 aq[2];
#pragma unroll
  for (int kc = 0; kc < 2; ++kc)
    aq[kc] = *(const s16x8*)(Qb + (size_t)(qw0 + r16) * DK + kc * 32 + g * 8);

  STAGE_KV(0, 0);
  STAGE_KV(1, KV_OF(1));

  f32x4 accd[4] = {};  // [dsub]: O^T[d=dsub*16+4g+rr][q=qw0+r16]
  float mrow = -INFINITY, lrow = 0.0f;
  u16x4 outA[4];  // parked segment-A output (stores deferred to epilogue)
  int srowA = 0;

  for (int t = 0; t < NT; ++t) {
    if (t == tilesA) {
      // flush segment A to registers; reset state; reload Q for segment B
      float inv = 1.0f / lrow;
      srowA = qw0 + r16;
#pragma unroll
      for (int dsub = 0; dsub < 4; ++dsub)
#pragma unroll
        for (int rr = 0; rr < 4; ++rr) outA[dsub][rr] = f2bf(accd[dsub][rr] * inv);
      qw0 = q0B + wave * 16;
#pragma unroll
      for (int kc = 0; kc < 2; ++kc)
        aq[kc] = *(const s16x8*)(Qb + (size_t)(qw0 + r16) * DK + kc * 32 + g * 8);
#pragma unroll
      for (int dsub = 0; dsub < 4; ++dsub) accd[dsub] = (f32x4){0.f, 0.f, 0.f, 0.f};
      mrow = -INFINITY;
      lrow = 0.0f;
    }

    int kv0 = KV_OF(t);

    // counted-vmcnt barrier: keep newest stage (4 loads) in flight
    if (t < NT - 1)
      asm volatile("s_waitcnt vmcnt(4)" ::: "memory");
    else
      asm volatile("s_waitcnt vmcnt(0)" ::: "memory");
    __builtin_amdgcn_s_barrier();
    __builtin_amdgcn_sched_barrier(0);
    if (t + 2 < NT) STAGE_KV((t + 2) % 3, KV_OF(t + 2));

    const char* Kc = (const char*)Klds[t % 3];
    const char* Vc = (const char*)Vlds[t % 3];

    // ---- QK^T (swapped): sf[nt][rr] = S[key = kv0+8g+4(nt&1)+rr+32(nt>>1)][q = qw0+r16]
    f32x4 sf[4] = {};
    __builtin_amdgcn_s_setprio(1);
#pragma unroll
    for (int kc = 0; kc < 2; ++kc) {
      s16x8 bk[4];
#pragma unroll
      for (int nt = 0; nt < 4; ++nt) {
        int row = rbase + 4 * (nt & 1) + 32 * (nt >> 1);
        int ch = (kc * 4 + g) ^ sk;
        bk[nt] = *(const s16x8*)(Kc + row * 128 + ch * 16);
      }
#pragma unroll
      for (int nt = 0; nt < 4; ++nt)
        sf[nt] = mfma16(bk[nt], aq[kc], sf[nt]);
    }
    __builtin_amdgcn_s_setprio(0);

    // ---- prefetch V fragments (hides LDS latency under softmax VALU)
    s16x8 av[2][4];
#pragma unroll
    for (int c = 0; c < 2; ++c)
#pragma unroll
      for (int dsub = 0; dsub < 4; ++dsub) {
        int row = dsub * 16 + r16;
        int ch = (c * 4 + g) ^ (row & 7);
        av[c][dsub] = *(const s16x8*)(Vc + row * 128 + ch * 16);
      }

    // ---- mask (diagonal tiles only; wave-uniform branch); finite sentinel
    if (kv0 + 63 > qw0) {
      int thr = qw0 + r16 - kv0 - 8 * g;  // key offset limit
#pragma unroll
      for (int nt = 0; nt < 4; ++nt) {
        int koff = 4 * (nt & 1) + 32 * (nt >> 1);
#pragma unroll
        for (int rr = 0; rr < 4; ++rr)
          if (koff + rr > thr) sf[nt][rr] = NEGS;
      }
    }

    // ---- online softmax (log2 domain)
    float tmax = NEGS;
#pragma unroll
    for (int nt = 0; nt < 4; ++nt)
#pragma unroll
      for (int rr = 0; rr < 4; ++rr) tmax = fmaxf(tmax, sf[nt][rr]);
    tmax = fmaxf(tmax, __shfl_xor(tmax, 16));
    tmax = fmaxf(tmax, __shfl_xor(tmax, 32));

    if (!__all(tmax <= mrow)) {  // exact defer: skip is numerically identical
      float mn = fmaxf(mrow, tmax);
      float fc = __builtin_amdgcn_exp2f(mrow - mn);
      lrow *= fc;
      mrow = mn;
#pragma unroll
      for (int dsub = 0; dsub < 4; ++dsub)
#pragma unroll
        for (int rr = 0; rr < 4; ++rr) accd[dsub][rr] *= fc;
    }

    float pf[4][4];
    float su = 0.0f;
#pragma unroll
    for (int nt = 0; nt < 4; ++nt)
#pragma unroll
      for (int rr = 0; rr < 4; ++rr) {
        float p = __builtin_amdgcn_exp2f(sf[nt][rr] - mrow);
        pf[nt][rr] = p;
        su += p;
      }
    su += __shfl_xor(su, 16);
    su += __shfl_xor(su, 32);
    lrow += su;

    // pack P^T fragments: chunk c holds keys c*32 + 8g..+7 in k-ascending order
    unsigned int pk[2][4];
#pragma unroll
    for (int c = 0; c < 2; ++c) {
      pk[c][0] = cvtpk(pf[2 * c][0], pf[2 * c][1]);
      pk[c][1] = cvtpk(pf[2 * c][2], pf[2 * c][3]);
      pk[c][2] = cvtpk(pf[2 * c + 1][0], pf[2 * c + 1][1]);
      pk[c][3] = cvtpk(pf[2 * c + 1][2], pf[2 * c + 1][3]);
    }

    // ---- PV (swapped): accd[dsub] += mfma(A=V^T rows, B=P^T)
    __builtin_amdgcn_s_setprio(1);
#pragma unroll
    for (int c = 0; c < 2; ++c) {
      s16x8 pb = __builtin_bit_cast(s16x8, *(u32x4*)pk[c]);
#pragma unroll
      for (int dsub = 0; dsub < 4; ++dsub)
        accd[dsub] = mfma16(av[c][dsub], pb, accd[dsub]);
    }
    __builtin_amdgcn_s_setprio(0);
  }

  // epilogue: write parked segment-A output, then segment B
#pragma unroll
  for (int dsub = 0; dsub < 4; ++dsub) {
    int d0 = dsub * 16 + 4 * g;
    *(u16x4*)&ctx[(((size_t)b * SS + srowA) * HH + h) * DK + d0] = outA[dsub];
  }
  int srow = qw0 + r16;
  float inv = 1.0f / lrow;
#pragma unroll
  for (int dsub = 0; dsub < 4; ++dsub) {
    int d0 = dsub * 16 + 4 * g;
    u16x4 o;
#pragma unroll
    for (int rr = 0; rr < 4; ++rr) o[rr] = f2bf(accd[dsub][rr] * inv);
    *(u16x4*)&ctx[(((size_t)b * SS + srow) * HH + h) * DK + d0] = o;
  }
#undef STAGE_KV
#undef KV_OF
}

extern "C" void kernel_launch(void* const* d_in, const int* in_sizes, int n_in,
                              void* d_out, int out_size, void* d_ws, size_t ws_size,
                              hipStream_t stream) {
  const float* q = (const float*)d_in[0];
  const float* k = (const float*)d_in[1];
  const float* v = (const float*)d_in[2];
  // d_in[3] = mask: exact causal tril, implemented in-kernel
  const float* Wq = (const float*)d_in[4];
  const float* bq = (const float*)d_in[5];
  const float* Wk = (const float*)d_in[6];
  const float* bk = (const float*)d_in[7];
  const float* Wv = (const float*)d_in[8];
  const float* bv = (const float*)d_in[9];
  const float* Wo = (const float*)d_in[10];
  const float* bo = (const float*)d_in[11];

  // Workspace layout (56 MB):
  //   [ 0, 8)  qb  -> reused as ctx    [ 8,16) kb    [16,24) vb -> reused as VhT
  //   [24,32) WT[4] (WqT,WkT,WvT,WoT; 2 MB each)
  //   [32,40) Qh   [40,48) Kh   [48,56) Vh
  char* ws = (char*)d_ws;
  const size_t MB = 1ull << 20;
  unsigned short* qb = (unsigned short*)(ws + 0 * MB);
  unsigned short* kb = (unsigned short*)(ws + 8 * MB);
  unsigned short* vb = (unsigned short*)(ws + 16 * MB);
  unsigned short* WTbase = (unsigned short*)(ws + 24 * MB);
  unsigned short* WoT = (unsigned short*)(ws + 30 * MB);
  unsigned short* Qh = (unsigned short*)(ws + 32 * MB);
  unsigned short* Kh = (unsigned short*)(ws + 40 * MB);
  unsigned short* Vh = (unsigned short*)(ws + 48 * MB);
  unsigned short* VhT = (unsigned short*)(ws + 16 * MB);  // reuse vb
  unsigned short* ctx = (unsigned short*)(ws + 0 * MB);   // reuse qb

  const int n4 = BB * SS * DD / 4;

  cvt3_kernel<<<dim3(n4 / 256, 3), 256, 0, stream>>>(q, k, v, qb, kb, vb);

  dim3 tb(32, 8);
  transpose_w4_kernel<<<dim3(32, 32, 4), tb, 0, stream>>>(Wq, Wk, Wv, Wo, WTbase);

  gemm_qkv_kernel<<<dim3(8, 96), 256, 0, stream>>>(qb, kb, vb, WTbase,
                                                   bq, bk, bv, Qh, Kh, Vh);

  transpose_v_kernel<<<dim3(SS / 32, DK / 32, BB * HH), tb, 0, stream>>>(Vh, VhT);

  attn_kernel<<<512, 256, 0, stream>>>(Qh, Kh, VhT, ctx);

  gemm_out_kernel<<<dim3(16, 32), 256, 0, stream>>>(ctx, WoT, bo, (float*)d_out);
}